// Round 9
// baseline (435.122 us; speedup 1.0000x reference)
//
#include <hip/hip_runtime.h>

// Problem constants
constexpr int NB = 8, NH = 8, NN = 1024, DK = 64, ED = 16;
constexpr long QSZ = (long)NB * NH * NN * DK;       // 4,194,304

typedef _Float16 h8 __attribute__((ext_vector_type(8)));
typedef _Float16 h4 __attribute__((ext_vector_type(4)));
typedef _Float16 h2 __attribute__((ext_vector_type(2)));
typedef float f4 __attribute__((ext_vector_type(4)));
typedef float fv16 __attribute__((ext_vector_type(16)));

// ws layout (bytes)
constexpr size_t OFF_QH = 0;                         // 8 MiB fp16 (pre-scaled by 0.125*log2e)
constexpr size_t OFF_KH = 8388608;                   // 8 MiB fp16
constexpr size_t OFF_VT = 16777216;                  // 8 MiB fp16 (transposed [bh][d][k])
constexpr size_t OFF_BIAS = 25165824;                // 16 MiB fp16 [b][q][kv] (bias*log2e, masked=-30000)
constexpr size_t OFF_BIAT = 41943040;                // 16 MiB fp16 [b][kv][q] (transposed copy)
constexpr size_t OFF_FLAG = 58720256;                // 4 B
constexpr size_t WS_NEED = OFF_FLAG + 4;

constexpr float LG2E = 1.4426950408889634f;          // log2(e)
constexpr float C2 = 2.8853900817779268f;            // 2*log2(e)
constexpr float QS = 0.125f * LG2E;                  // fold 1/sqrt(dk) and log2e into Q

static __device__ __forceinline__ float fexp2(float x) {
  float r; asm("v_exp_f32 %0, %1" : "=v"(r) : "v"(x)); return r;
}
static __device__ __forceinline__ float frcp(float x) {
  float r; asm("v_rcp_f32 %0, %1" : "=v"(r) : "v"(x)); return r;
}
static __device__ __forceinline__ h2 pkrtz(float a, float b) {
  return __builtin_bit_cast(h2, __builtin_amdgcn_cvt_pkrtz(a, b));
}

// ---------- prep: Q (x 0.125*log2e) and K -> fp16, same layout ----------
__global__ __launch_bounds__(256) void k_prep_qk(
    const float* __restrict__ Q, const float* __restrict__ K,
    _Float16* __restrict__ Qh, _Float16* __restrict__ Kh) {
  int i = blockIdx.x * 256 + threadIdx.x;
  const int n4 = (int)(QSZ / 4);
  if (i < n4) {
    float4 v = reinterpret_cast<const float4*>(Q)[i];
    h4 o; o[0] = (_Float16)(v.x * QS); o[1] = (_Float16)(v.y * QS);
          o[2] = (_Float16)(v.z * QS); o[3] = (_Float16)(v.w * QS);
    reinterpret_cast<h4*>(Qh)[i] = o;
  } else {
    int j = i - n4;
    float4 v = reinterpret_cast<const float4*>(K)[j];
    h4 o; o[0] = (_Float16)v.x; o[1] = (_Float16)v.y;
          o[2] = (_Float16)v.z; o[3] = (_Float16)v.w;
    reinterpret_cast<h4*>(Kh)[j] = o;
  }
}

// ---------- prep: V [bh][k][d] fp32 -> Vt [bh][d][k] fp16 ----------
__global__ __launch_bounds__(256) void k_prep_vt(
    const float* __restrict__ V, _Float16* __restrict__ Vt) {
  int wid = (blockIdx.x * 256 + threadIdx.x) >> 6;   // 4096 waves
  int lane = threadIdx.x & 63;
  int bh = wid >> 6;
  int k0 = (wid & 63) << 4;
  const float* Vb = V + (long)bh * NN * DK;
  _Float16* Vo = Vt + (long)bh * DK * NN + (long)lane * NN + k0;
  h8 p0, p1;
#pragma unroll
  for (int i = 0; i < 16; ++i) {
    float v = Vb[(long)(k0 + i) * DK + lane];
    if (i < 8) p0[i] = (_Float16)v; else p1[i - 8] = (_Float16)v;
  }
  *reinterpret_cast<h8*>(Vo) = p0;
  *reinterpret_cast<h8*>(Vo + 8) = p1;
}

// ---------- detect mask element width (bool bytes vs int32) ----------
__global__ void k_detect(const unsigned char* __restrict__ m, int* __restrict__ flag) {
  int t = threadIdx.x;
  int any = 0;
  for (int i = t; i < 4096; i += 256)
    if ((i & 3) && m[i]) any = 1;          // int32 0/1 never has nonzero at %4!=0
  unsigned long long b = __ballot(any);
  if ((t & 63) == 0 && b) atomicOr(flag, 1);
}

// ---------- edge-bias MLP + mask fold (unchanged from R8) ----------
__global__ __launch_bounds__(256, 3) void k_bias(
    const float* __restrict__ edge, const void* __restrict__ maskp,
    const float* __restrict__ W1, const float* __restrict__ b1,
    const float* __restrict__ W2, const float* __restrict__ b2,
    const int* __restrict__ flag, _Float16* __restrict__ biasM) {
  int bq = blockIdx.x;
  int w = threadIdx.x >> 6, l = threadIdx.x & 63;
  int h = l >> 5, c31 = l & 31;
  bool isbool = (*flag != 0);
  h8 aw0, aw1;
#pragma unroll
  for (int j = 0; j < 8; ++j) {
    aw0[j] = (_Float16)(W1[(8 * h + j) * 64 + 0  + c31] * C2);
    aw1[j] = (_Float16)(W1[(8 * h + j) * 64 + 32 + c31] * C2);
  }
  h2 pb[16], pw[16];
  float sw = 0.f;
#pragma unroll
  for (int r = 0; r < 16; ++r) {
    int dr = (r & 3) + 8 * (r >> 2) + 4 * h;
    float b0 = b1[dr] * C2, b1v = b1[32 + dr] * C2;
    float w0 = W2[dr], w1v = W2[32 + dr];
    pb[r] = pkrtz(b0, b1v);
    pw[r] = pkrtz(w0, w1v);
    sw += w0 + w1v;
  }
  sw += __shfl_xor(sw, 32, 64);
  float base = (sw + b2[0]) * LG2E;

  const float* erow = edge + (long)bq * NN * ED;
  const float4* erow4 = reinterpret_cast<const float4*>(erow);
  _Float16* orow = biasM + (long)bq * NN;
  const int* mrowi = (const int*)maskp + (long)bq * NN;
  const unsigned char* mrowb = (const unsigned char*)maskp + (long)bq * NN;

  fv16 z;
#pragma unroll
  for (int r = 0; r < 16; ++r) z[r] = 0.f;

  int kbase = w * 256;
  float4 e0a = erow4[(kbase + c31) * 4 + 2 * h];
  float4 e0b = erow4[(kbase + c31) * 4 + 2 * h + 1];
  float4 e1a = erow4[(kbase + 32 + c31) * 4 + 2 * h];
  float4 e1b = erow4[(kbase + 32 + c31) * 4 + 2 * h + 1];
#pragma unroll
  for (int p = 0; p < 4; ++p) {
    float4 n0a, n0b, n1a, n1b;
    if (p < 3) {
      int nb = kbase + 64;
      n0a = erow4[(nb + c31) * 4 + 2 * h];
      n0b = erow4[(nb + c31) * 4 + 2 * h + 1];
      n1a = erow4[(nb + 32 + c31) * 4 + 2 * h];
      n1b = erow4[(nb + 32 + c31) * 4 + 2 * h + 1];
    }
    union { h8 v; h2 q[4]; } u0, u1;
    u0.q[0] = pkrtz(e0a.x, e0a.y); u0.q[1] = pkrtz(e0a.z, e0a.w);
    u0.q[2] = pkrtz(e0b.x, e0b.y); u0.q[3] = pkrtz(e0b.z, e0b.w);
    u1.q[0] = pkrtz(e1a.x, e1a.y); u1.q[1] = pkrtz(e1a.z, e1a.w);
    u1.q[2] = pkrtz(e1b.x, e1b.y); u1.q[3] = pkrtz(e1b.z, e1b.w);
    float a00 = 0.f, a01 = 0.f, a10 = 0.f, a11 = 0.f;
    {
      fv16 hA0 = __builtin_amdgcn_mfma_f32_32x32x16_f16(aw0, u0.v, z, 0, 0, 0);
      fv16 hA1 = __builtin_amdgcn_mfma_f32_32x32x16_f16(aw0, u1.v, z, 0, 0, 0);
#pragma unroll
      for (int r = 0; r < 16; ++r) {
        float bb = (float)pb[r][0];
        float ww = (float)pw[r][0];
        if (r & 1) {
          a01 = fmaf(ww, frcp(fexp2(hA0[r] + bb) + 1.f), a01);
          a11 = fmaf(ww, frcp(fexp2(hA1[r] + bb) + 1.f), a11);
        } else {
          a00 = fmaf(ww, frcp(fexp2(hA0[r] + bb) + 1.f), a00);
          a10 = fmaf(ww, frcp(fexp2(hA1[r] + bb) + 1.f), a10);
        }
      }
    }
    {
      fv16 hB0 = __builtin_amdgcn_mfma_f32_32x32x16_f16(aw1, u0.v, z, 0, 0, 0);
      fv16 hB1 = __builtin_amdgcn_mfma_f32_32x32x16_f16(aw1, u1.v, z, 0, 0, 0);
#pragma unroll
      for (int r = 0; r < 16; ++r) {
        float bb = (float)pb[r][1];
        float ww = (float)pw[r][1];
        if (r & 1) {
          a01 = fmaf(ww, frcp(fexp2(hB0[r] + bb) + 1.f), a01);
          a11 = fmaf(ww, frcp(fexp2(hB1[r] + bb) + 1.f), a11);
        } else {
          a00 = fmaf(ww, frcp(fexp2(hB0[r] + bb) + 1.f), a00);
          a10 = fmaf(ww, frcp(fexp2(hB1[r] + bb) + 1.f), a10);
        }
      }
    }
    float p0 = a00 + a01;
    float p1 = a10 + a11;
    p0 += __shfl_xor(p0, 32, 64);
    p1 += __shfl_xor(p1, 32, 64);
    float part = h ? p1 : p0;
    int idx = kbase + 32 * h + c31;
    int m = isbool ? (int)mrowb[idx] : mrowi[idx];
    orow[idx] = m ? (_Float16)(-30000.0f) : (_Float16)fmaf(-C2, part, base);
    e0a = n0a; e0b = n0b; e1a = n1a; e1b = n1b;
    kbase += 64;
  }
}

// ---------- bias transpose: [b][q][kv] -> [b][kv][q], 64x64 LDS tiles ----------
__global__ __launch_bounds__(256) void k_btr(
    const _Float16* __restrict__ B, _Float16* __restrict__ BT) {
  int b = blockIdx.x >> 8;             // 8 batches x 256 tiles
  int t = blockIdx.x & 255;
  int tq = (t >> 4) * 64, tk = (t & 15) * 64;
  __shared__ _Float16 tile[64][72];    // pitch 144B (16B-aligned rows)
  const _Float16* src = B + (long)b * NN * NN;
  _Float16* dst = BT + (long)b * NN * NN;
  int tid = threadIdx.x;
  int r = tid >> 2, c8 = (tid & 3) * 16;
  *reinterpret_cast<h8*>(&tile[r][c8]) =
      *reinterpret_cast<const h8*>(&src[(long)(tq + r) * NN + tk + c8]);
  *reinterpret_cast<h8*>(&tile[r][c8 + 8]) =
      *reinterpret_cast<const h8*>(&src[(long)(tq + r) * NN + tk + c8 + 8]);
  __syncthreads();
  h8 o0, o1;
#pragma unroll
  for (int m = 0; m < 8; ++m) o0[m] = tile[c8 + m][r];
#pragma unroll
  for (int m = 0; m < 8; ++m) o1[m] = tile[c8 + 8 + m][r];
  *reinterpret_cast<h8*>(&dst[(long)(tk + r) * NN + tq + c8]) = o0;
  *reinterpret_cast<h8*>(&dst[(long)(tk + r) * NN + tq + c8 + 8]) = o1;
}

// ---------- fused attention: deep ping-pong prefetch + h4 transposed-bias loads ----------
// acc[j] = S'[q0+4g+j][kv+s]; bias via biasT[kv+s][q0+4g..+3] (one h4 per 16-kv tile)
#define LDK64(K0,K1,K2,K3,K4,K5,K6,K7,B0,B1,B2,B3,cc) do { long c_ = (cc); \
  K0 = *reinterpret_cast<const h8*>(Kg + c_ * DK);        K1 = *reinterpret_cast<const h8*>(Kg + c_ * DK + 32); \
  K2 = *reinterpret_cast<const h8*>(Kg + (c_ + 16) * DK); K3 = *reinterpret_cast<const h8*>(Kg + (c_ + 16) * DK + 32); \
  K4 = *reinterpret_cast<const h8*>(Kg + (c_ + 32) * DK); K5 = *reinterpret_cast<const h8*>(Kg + (c_ + 32) * DK + 32); \
  K6 = *reinterpret_cast<const h8*>(Kg + (c_ + 48) * DK); K7 = *reinterpret_cast<const h8*>(Kg + (c_ + 48) * DK + 32); \
  B0 = *reinterpret_cast<const h4*>(Bt + c_ * NN);        B1 = *reinterpret_cast<const h4*>(Bt + (c_ + 16) * NN); \
  B2 = *reinterpret_cast<const h4*>(Bt + (c_ + 32) * NN); B3 = *reinterpret_cast<const h4*>(Bt + (c_ + 48) * NN); \
} while (0)

#define LDK32(K0,K1,K2,K3,B0,B1,cc) do { long c_ = (cc); \
  K0 = *reinterpret_cast<const h8*>(Kg + c_ * DK);        K1 = *reinterpret_cast<const h8*>(Kg + c_ * DK + 32); \
  K2 = *reinterpret_cast<const h8*>(Kg + (c_ + 16) * DK); K3 = *reinterpret_cast<const h8*>(Kg + (c_ + 16) * DK + 32); \
  B0 = *reinterpret_cast<const h4*>(Bt + c_ * NN);        B1 = *reinterpret_cast<const h4*>(Bt + (c_ + 16) * NN); \
} while (0)

#define P1CT(K0,K1,BB) do { \
  f4 acc = __builtin_amdgcn_mfma_f32_16x16x32_f16(aQ0, K0, z4, 0, 0, 0); \
  acc = __builtin_amdgcn_mfma_f32_16x16x32_f16(aQ1, K1, acc, 0, 0, 0); \
  ls0 += fexp2(acc[0] + (float)BB[0]); \
  ls1 += fexp2(acc[1] + (float)BB[1]); \
  ls2 += fexp2(acc[2] + (float)BB[2]); \
  ls3 += fexp2(acc[3] + (float)BB[3]); \
} while (0)

#define P2CT(K0,K1,BB,kvb,lofs) do { \
  f4 acc = __builtin_amdgcn_mfma_f32_16x16x32_f16(aQ0, K0, z4, 0, 0, 0); \
  acc = __builtin_amdgcn_mfma_f32_16x16x32_f16(aQ1, K1, acc, 0, 0, 0); \
  float p0 = fexp2(acc[0] + (float)BB[0]) * iv0; \
  float p1 = fexp2(acc[1] + (float)BB[1]) * iv1; \
  float p2 = fexp2(acc[2] + (float)BB[2]) * iv2; \
  float p3 = fexp2(acc[3] + (float)BB[3]) * iv3; \
  attnw[(4 * g + 0) * NN + (kvb) + s] = p0; \
  attnw[(4 * g + 1) * NN + (kvb) + s] = p1; \
  attnw[(4 * g + 2) * NN + (kvb) + s] = p2; \
  attnw[(4 * g + 3) * NN + (kvb) + s] = p3; \
  plds[w][4 * g + 0][(lofs) + s] = (_Float16)p0; \
  plds[w][4 * g + 1][(lofs) + s] = (_Float16)p1; \
  plds[w][4 * g + 2][(lofs) + s] = (_Float16)p2; \
  plds[w][4 * g + 3][(lofs) + s] = (_Float16)p3; \
} while (0)

#define PV32(cb) do { \
  h8 aP = *reinterpret_cast<const h8*>(&plds[w][s][8 * g]); \
  const _Float16* vp = Vb + (long)s * NN + (cb) + 8 * g; \
  h8 bv0 = *reinterpret_cast<const h8*>(vp); \
  h8 bv1 = *reinterpret_cast<const h8*>(vp + 16 * NN); \
  h8 bv2 = *reinterpret_cast<const h8*>(vp + 32 * NN); \
  h8 bv3 = *reinterpret_cast<const h8*>(vp + 48 * NN); \
  ca0 = __builtin_amdgcn_mfma_f32_16x16x32_f16(aP, bv0, ca0, 0, 0, 0); \
  ca1 = __builtin_amdgcn_mfma_f32_16x16x32_f16(aP, bv1, ca1, 0, 0, 0); \
  ca2 = __builtin_amdgcn_mfma_f32_16x16x32_f16(aP, bv2, ca2, 0, 0, 0); \
  ca3 = __builtin_amdgcn_mfma_f32_16x16x32_f16(aP, bv3, ca3, 0, 0, 0); \
} while (0)

__global__ __launch_bounds__(256, 4) void k_attn(
    const _Float16* __restrict__ Qh, const _Float16* __restrict__ Kh,
    const _Float16* __restrict__ Vt, const _Float16* __restrict__ biasT,
    float* __restrict__ ctx, float* __restrict__ attn) {
  int bid = blockIdx.x;
  int b = bid & 7;           // XCD-pinned batch
  int t = bid >> 3;
  int hh = t & 7;
  int qb = t >> 3;
  int bh = b * 8 + hh;
  int w = threadIdx.x >> 6, l = threadIdx.x & 63;
  int g = l >> 4, s = l & 15;
  int q0 = qb * 64 + w * 16;
  const _Float16* Qw = Qh + ((long)bh * NN + q0) * DK;
  const _Float16* Kg = Kh + (long)bh * NN * DK + (long)s * DK + 8 * g;
  const _Float16* Vb = Vt + (long)bh * DK * NN;
  const _Float16* Bt = biasT + (long)b * NN * NN + (long)s * NN + q0 + 4 * g;
  h8 aQ0 = *reinterpret_cast<const h8*>(Qw + s * DK + 8 * g);
  h8 aQ1 = *reinterpret_cast<const h8*>(Qw + s * DK + 32 + 8 * g);
  const f4 z4 = {0.f, 0.f, 0.f, 0.f};

  // ---- pass 1: 64-kv superchunk ping-pong (prefetch distance ~1 superchunk) ----
  float ls0 = 0.f, ls1 = 0.f, ls2 = 0.f, ls3 = 0.f;
  h8 xk0, xk1, xk2, xk3, xk4, xk5, xk6, xk7;
  h8 yk0, yk1, yk2, yk3, yk4, yk5, yk6, yk7;
  h4 xb0, xb1, xb2, xb3, yb0, yb1, yb2, yb3;
  LDK64(xk0, xk1, xk2, xk3, xk4, xk5, xk6, xk7, xb0, xb1, xb2, xb3, 0);
  for (int c = 0; c < NN; c += 128) {
    LDK64(yk0, yk1, yk2, yk3, yk4, yk5, yk6, yk7, yb0, yb1, yb2, yb3, c + 64);
    P1CT(xk0, xk1, xb0); P1CT(xk2, xk3, xb1); P1CT(xk4, xk5, xb2); P1CT(xk6, xk7, xb3);
    LDK64(xk0, xk1, xk2, xk3, xk4, xk5, xk6, xk7, xb0, xb1, xb2, xb3, (c + 128) & (NN - 1));
    P1CT(yk0, yk1, yb0); P1CT(yk2, yk3, yb1); P1CT(yk4, yk5, yb2); P1CT(yk6, yk7, yb3);
  }
#pragma unroll
  for (int m = 1; m < 16; m <<= 1) {
    ls0 += __shfl_xor(ls0, m, 64);
    ls1 += __shfl_xor(ls1, m, 64);
    ls2 += __shfl_xor(ls2, m, 64);
    ls3 += __shfl_xor(ls3, m, 64);
  }
  float iv0 = frcp(ls0), iv1 = frcp(ls1), iv2 = frcp(ls2), iv3 = frcp(ls3);

  // ---- pass 2: 32-kv ping-pong; attn stores + LDS P + PV ----
  __shared__ _Float16 plds[4][16][40];
  f4 ca0 = {0.f, 0.f, 0.f, 0.f}, ca1 = {0.f, 0.f, 0.f, 0.f};
  f4 ca2 = {0.f, 0.f, 0.f, 0.f}, ca3 = {0.f, 0.f, 0.f, 0.f};
  float* attnw = attn + ((long)bh * NN + q0) * NN;
  LDK32(xk0, xk1, xk2, xk3, xb0, xb1, 0);
  for (int c = 0; c < NN; c += 64) {
    LDK32(yk0, yk1, yk2, yk3, yb0, yb1, c + 32);
    P2CT(xk0, xk1, xb0, c, 0);
    P2CT(xk2, xk3, xb1, c + 16, 16);
    PV32(c);
    LDK32(xk0, xk1, xk2, xk3, xb0, xb1, (c + 64) & (NN - 1));
    P2CT(yk0, yk1, yb0, c + 32, 0);
    P2CT(yk2, yk3, yb1, c + 48, 16);
    PV32(c + 32);
  }
  float* cw = ctx + ((long)bh * NN + q0) * DK;
#pragma unroll
  for (int j = 0; j < 4; ++j) {
    cw[(4 * g + j) * DK + 0  + s] = ca0[j];
    cw[(4 * g + j) * DK + 16 + s] = ca1[j];
    cw[(4 * g + j) * DK + 32 + s] = ca2[j];
    cw[(4 * g + j) * DK + 48 + s] = ca3[j];
  }
}

extern "C" void kernel_launch(void* const* d_in, const int* in_sizes, int n_in,
                              void* d_out, int out_size, void* d_ws, size_t ws_size,
                              hipStream_t stream) {
  const float* Q = (const float*)d_in[0];
  const float* K = (const float*)d_in[1];
  const float* V = (const float*)d_in[2];
  const void* mask = d_in[3];
  const float* edge = (const float*)d_in[4];
  const float* W1 = (const float*)d_in[5];
  const float* b1 = (const float*)d_in[6];
  const float* W2 = (const float*)d_in[7];
  const float* b2 = (const float*)d_in[8];
  float* ctx = (float*)d_out;
  float* attn = ctx + QSZ;                  // outputs: context then attn
  char* ws = (char*)d_ws;
  if (ws_size < WS_NEED) return;
  _Float16* Qh = (_Float16*)(ws + OFF_QH);
  _Float16* Kh = (_Float16*)(ws + OFF_KH);
  _Float16* Vt = (_Float16*)(ws + OFF_VT);
  _Float16* biasM = (_Float16*)(ws + OFF_BIAS);
  _Float16* biasT = (_Float16*)(ws + OFF_BIAT);
  int* flag = (int*)(ws + OFF_FLAG);

  (void)hipMemsetAsync(flag, 0, 4, stream);
  k_detect<<<1, 256, 0, stream>>>((const unsigned char*)mask, flag);
  k_prep_qk<<<8192, 256, 0, stream>>>(Q, K, Qh, Kh);
  k_prep_vt<<<1024, 256, 0, stream>>>(V, Vt);
  k_bias<<<8192, 256, 0, stream>>>(edge, mask, W1, b1, W2, b2, flag, biasM);
  k_btr<<<2048, 256, 0, stream>>>(biasM, biasT);
  k_attn<<<1024, 256, 0, stream>>>(Qh, Kh, Vt, biasT, ctx, attn);
}

// Round 10
// 382.012 us; speedup vs baseline: 1.1390x; 1.1390x over previous
//
#include <hip/hip_runtime.h>

// Problem constants
constexpr int NB = 8, NH = 8, NN = 1024, DK = 64, ED = 16;
constexpr long QSZ = (long)NB * NH * NN * DK;       // 4,194,304

typedef _Float16 h8 __attribute__((ext_vector_type(8)));
typedef _Float16 h4 __attribute__((ext_vector_type(4)));
typedef _Float16 h2 __attribute__((ext_vector_type(2)));
typedef float f4 __attribute__((ext_vector_type(4)));
typedef float fv16 __attribute__((ext_vector_type(16)));

// ws layout (bytes)
constexpr size_t OFF_QH = 0;                         // 8 MiB fp16 (pre-scaled by 0.125*log2e)
constexpr size_t OFF_KH = 8388608;                   // 8 MiB fp16
constexpr size_t OFF_VT = 16777216;                  // 8 MiB fp16 (transposed [bh][d][k])
constexpr size_t OFF_BIAS = 25165824;                // 16 MiB fp16 (bias*log2e, masked=-30000)
constexpr size_t OFF_FLAG = 58720256;                // 4 B
constexpr size_t WS_NEED = OFF_FLAG + 4;

constexpr float LG2E = 1.4426950408889634f;          // log2(e)
constexpr float C2 = 2.8853900817779268f;            // 2*log2(e)
constexpr float QS = 0.125f * LG2E;                  // fold 1/sqrt(dk) and log2e into Q

static __device__ __forceinline__ float fexp2(float x) {
  float r; asm("v_exp_f32 %0, %1" : "=v"(r) : "v"(x)); return r;
}
static __device__ __forceinline__ float frcp(float x) {
  float r; asm("v_rcp_f32 %0, %1" : "=v"(r) : "v"(x)); return r;
}
static __device__ __forceinline__ h2 pkrtz(float a, float b) {
  return __builtin_bit_cast(h2, __builtin_amdgcn_cvt_pkrtz(a, b));
}

// ---------- prep: Q (x 0.125*log2e) and K -> fp16, same layout ----------
__global__ __launch_bounds__(256) void k_prep_qk(
    const float* __restrict__ Q, const float* __restrict__ K,
    _Float16* __restrict__ Qh, _Float16* __restrict__ Kh) {
  int i = blockIdx.x * 256 + threadIdx.x;
  const int n4 = (int)(QSZ / 4);
  if (i < n4) {
    float4 v = reinterpret_cast<const float4*>(Q)[i];
    h4 o; o[0] = (_Float16)(v.x * QS); o[1] = (_Float16)(v.y * QS);
          o[2] = (_Float16)(v.z * QS); o[3] = (_Float16)(v.w * QS);
    reinterpret_cast<h4*>(Qh)[i] = o;
  } else {
    int j = i - n4;
    float4 v = reinterpret_cast<const float4*>(K)[j];
    h4 o; o[0] = (_Float16)v.x; o[1] = (_Float16)v.y;
          o[2] = (_Float16)v.z; o[3] = (_Float16)v.w;
    reinterpret_cast<h4*>(Kh)[j] = o;
  }
}

// ---------- prep: V [bh][k][d] fp32 -> Vt [bh][d][k] fp16 ----------
__global__ __launch_bounds__(256) void k_prep_vt(
    const float* __restrict__ V, _Float16* __restrict__ Vt) {
  int wid = (blockIdx.x * 256 + threadIdx.x) >> 6;   // 4096 waves
  int lane = threadIdx.x & 63;
  int bh = wid >> 6;
  int k0 = (wid & 63) << 4;
  const float* Vb = V + (long)bh * NN * DK;
  _Float16* Vo = Vt + (long)bh * DK * NN + (long)lane * NN + k0;
  h8 p0, p1;
#pragma unroll
  for (int i = 0; i < 16; ++i) {
    float v = Vb[(long)(k0 + i) * DK + lane];
    if (i < 8) p0[i] = (_Float16)v; else p1[i - 8] = (_Float16)v;
  }
  *reinterpret_cast<h8*>(Vo) = p0;
  *reinterpret_cast<h8*>(Vo + 8) = p1;
}

// ---------- detect mask element width (bool bytes vs int32); no pre-zero needed ----------
__global__ void k_detect(const unsigned char* __restrict__ m, int* __restrict__ flag) {
  __shared__ int sh[4];
  int t = threadIdx.x;
  int any = 0;
  for (int i = t; i < 4096; i += 256)
    if ((i & 3) && m[i]) any = 1;          // int32 0/1 never has nonzero at %4!=0
  unsigned long long b = __ballot(any);
  if ((t & 63) == 0) sh[t >> 6] = (b != 0) ? 1 : 0;
  __syncthreads();
  if (t == 0) flag[0] = sh[0] | sh[1] | sh[2] | sh[3];
}

// ---------- edge-bias MLP + mask fold (unchanged from R8) ----------
__global__ __launch_bounds__(256, 3) void k_bias(
    const float* __restrict__ edge, const void* __restrict__ maskp,
    const float* __restrict__ W1, const float* __restrict__ b1,
    const float* __restrict__ W2, const float* __restrict__ b2,
    const int* __restrict__ flag, _Float16* __restrict__ biasM) {
  int bq = blockIdx.x;
  int w = threadIdx.x >> 6, l = threadIdx.x & 63;
  int h = l >> 5, c31 = l & 31;
  bool isbool = (*flag != 0);
  h8 aw0, aw1;
#pragma unroll
  for (int j = 0; j < 8; ++j) {
    aw0[j] = (_Float16)(W1[(8 * h + j) * 64 + 0  + c31] * C2);
    aw1[j] = (_Float16)(W1[(8 * h + j) * 64 + 32 + c31] * C2);
  }
  h2 pb[16], pw[16];
  float sw = 0.f;
#pragma unroll
  for (int r = 0; r < 16; ++r) {
    int dr = (r & 3) + 8 * (r >> 2) + 4 * h;
    float b0 = b1[dr] * C2, b1v = b1[32 + dr] * C2;
    float w0 = W2[dr], w1v = W2[32 + dr];
    pb[r] = pkrtz(b0, b1v);
    pw[r] = pkrtz(w0, w1v);
    sw += w0 + w1v;
  }
  sw += __shfl_xor(sw, 32, 64);
  float base = (sw + b2[0]) * LG2E;

  const float* erow = edge + (long)bq * NN * ED;
  const float4* erow4 = reinterpret_cast<const float4*>(erow);
  _Float16* orow = biasM + (long)bq * NN;
  const int* mrowi = (const int*)maskp + (long)bq * NN;
  const unsigned char* mrowb = (const unsigned char*)maskp + (long)bq * NN;

  fv16 z;
#pragma unroll
  for (int r = 0; r < 16; ++r) z[r] = 0.f;

  int kbase = w * 256;
  float4 e0a = erow4[(kbase + c31) * 4 + 2 * h];
  float4 e0b = erow4[(kbase + c31) * 4 + 2 * h + 1];
  float4 e1a = erow4[(kbase + 32 + c31) * 4 + 2 * h];
  float4 e1b = erow4[(kbase + 32 + c31) * 4 + 2 * h + 1];
#pragma unroll
  for (int p = 0; p < 4; ++p) {
    float4 n0a, n0b, n1a, n1b;
    if (p < 3) {
      int nb = kbase + 64;
      n0a = erow4[(nb + c31) * 4 + 2 * h];
      n0b = erow4[(nb + c31) * 4 + 2 * h + 1];
      n1a = erow4[(nb + 32 + c31) * 4 + 2 * h];
      n1b = erow4[(nb + 32 + c31) * 4 + 2 * h + 1];
    }
    union { h8 v; h2 q[4]; } u0, u1;
    u0.q[0] = pkrtz(e0a.x, e0a.y); u0.q[1] = pkrtz(e0a.z, e0a.w);
    u0.q[2] = pkrtz(e0b.x, e0b.y); u0.q[3] = pkrtz(e0b.z, e0b.w);
    u1.q[0] = pkrtz(e1a.x, e1a.y); u1.q[1] = pkrtz(e1a.z, e1a.w);
    u1.q[2] = pkrtz(e1b.x, e1b.y); u1.q[3] = pkrtz(e1b.z, e1b.w);
    float a00 = 0.f, a01 = 0.f, a10 = 0.f, a11 = 0.f;
    {
      fv16 hA0 = __builtin_amdgcn_mfma_f32_32x32x16_f16(aw0, u0.v, z, 0, 0, 0);
      fv16 hA1 = __builtin_amdgcn_mfma_f32_32x32x16_f16(aw0, u1.v, z, 0, 0, 0);
#pragma unroll
      for (int r = 0; r < 16; ++r) {
        float bb = (float)pb[r][0];
        float ww = (float)pw[r][0];
        if (r & 1) {
          a01 = fmaf(ww, frcp(fexp2(hA0[r] + bb) + 1.f), a01);
          a11 = fmaf(ww, frcp(fexp2(hA1[r] + bb) + 1.f), a11);
        } else {
          a00 = fmaf(ww, frcp(fexp2(hA0[r] + bb) + 1.f), a00);
          a10 = fmaf(ww, frcp(fexp2(hA1[r] + bb) + 1.f), a10);
        }
      }
    }
    {
      fv16 hB0 = __builtin_amdgcn_mfma_f32_32x32x16_f16(aw1, u0.v, z, 0, 0, 0);
      fv16 hB1 = __builtin_amdgcn_mfma_f32_32x32x16_f16(aw1, u1.v, z, 0, 0, 0);
#pragma unroll
      for (int r = 0; r < 16; ++r) {
        float bb = (float)pb[r][1];
        float ww = (float)pw[r][1];
        if (r & 1) {
          a01 = fmaf(ww, frcp(fexp2(hB0[r] + bb) + 1.f), a01);
          a11 = fmaf(ww, frcp(fexp2(hB1[r] + bb) + 1.f), a11);
        } else {
          a00 = fmaf(ww, frcp(fexp2(hB0[r] + bb) + 1.f), a00);
          a10 = fmaf(ww, frcp(fexp2(hB1[r] + bb) + 1.f), a10);
        }
      }
    }
    float p0 = a00 + a01;
    float p1 = a10 + a11;
    p0 += __shfl_xor(p0, 32, 64);
    p1 += __shfl_xor(p1, 32, 64);
    float part = h ? p1 : p0;
    int idx = kbase + 32 * h + c31;
    int m = isbool ? (int)mrowb[idx] : mrowi[idx];
    orow[idx] = m ? (_Float16)(-30000.0f) : (_Float16)fmaf(-C2, part, base);
    e0a = n0a; e0b = n0b; e1a = n1a; e1b = n1b;
    kbase += 64;
  }
}

// ---------- fused attention (R8 base; pass-2 stores via f32 LDS tile, full-line f4) ----------
__global__ __launch_bounds__(256) void k_attn(
    const _Float16* __restrict__ Qh, const _Float16* __restrict__ Kh,
    const _Float16* __restrict__ Vt, const _Float16* __restrict__ biasH,
    float* __restrict__ ctx, float* __restrict__ attn) {
  int bid = blockIdx.x;
  int b = bid & 7;           // XCD-pinned batch
  int t = bid >> 3;
  int hh = t & 7;
  int qb = t >> 3;
  int bh = b * 8 + hh;
  int w = threadIdx.x >> 6, l = threadIdx.x & 63;
  int g = l >> 4, s = l & 15;
  int q0 = qb * 64 + w * 16;
  const _Float16* Qw = Qh + ((long)bh * NN + q0) * DK;
  const _Float16* Kb = Kh + (long)bh * NN * DK;
  const _Float16* Vb = Vt + (long)bh * DK * NN;
  const _Float16* bias0 = biasH + (long)b * NN * NN + (long)q0 * NN;
  const _Float16* br0 = bias0 + (long)(4 * g + 0) * NN + s;
  const _Float16* br1 = bias0 + (long)(4 * g + 1) * NN + s;
  const _Float16* br2 = bias0 + (long)(4 * g + 2) * NN + s;
  const _Float16* br3 = bias0 + (long)(4 * g + 3) * NN + s;
  h8 aQ0 = *reinterpret_cast<const h8*>(Qw + s * DK + 8 * g);
  h8 aQ1 = *reinterpret_cast<const h8*>(Qw + s * DK + 32 + 8 * g);

  // ---- pass 1: row sums of exp2(S'), depth-1 prefetch of K + bias ----
  float ls0 = 0.f, ls1 = 0.f, ls2 = 0.f, ls3 = 0.f;
  h8 ka0, ka1, kb0, kb1, na0, na1, nb0, nb1;
  _Float16 bc[8], bn[8];
  {
    const _Float16* kp = Kb + (long)s * DK + 8 * g;
    ka0 = *reinterpret_cast<const h8*>(kp);
    ka1 = *reinterpret_cast<const h8*>(kp + 32);
    const _Float16* kq = Kb + (long)(16 + s) * DK + 8 * g;
    kb0 = *reinterpret_cast<const h8*>(kq);
    kb1 = *reinterpret_cast<const h8*>(kq + 32);
    bc[0] = br0[0];  bc[1] = br1[0];  bc[2] = br2[0];  bc[3] = br3[0];
    bc[4] = br0[16]; bc[5] = br1[16]; bc[6] = br2[16]; bc[7] = br3[16];
  }
  for (int c0 = 0; c0 < NN; c0 += 32) {
    int cn = (c0 + 32) & (NN - 1);       // wrapped: branchless, always valid
    const _Float16* kp = Kb + (long)(cn + s) * DK + 8 * g;
    na0 = *reinterpret_cast<const h8*>(kp);
    na1 = *reinterpret_cast<const h8*>(kp + 32);
    const _Float16* kq = Kb + (long)(cn + 16 + s) * DK + 8 * g;
    nb0 = *reinterpret_cast<const h8*>(kq);
    nb1 = *reinterpret_cast<const h8*>(kq + 32);
    bn[0] = br0[cn];      bn[1] = br1[cn];      bn[2] = br2[cn];      bn[3] = br3[cn];
    bn[4] = br0[cn + 16]; bn[5] = br1[cn + 16]; bn[6] = br2[cn + 16]; bn[7] = br3[cn + 16];
    f4 z = {0.f, 0.f, 0.f, 0.f};
    f4 acc = __builtin_amdgcn_mfma_f32_16x16x32_f16(aQ0, ka0, z, 0, 0, 0);
    acc = __builtin_amdgcn_mfma_f32_16x16x32_f16(aQ1, ka1, acc, 0, 0, 0);
    ls0 += fexp2(acc[0] + (float)bc[0]);
    ls1 += fexp2(acc[1] + (float)bc[1]);
    ls2 += fexp2(acc[2] + (float)bc[2]);
    ls3 += fexp2(acc[3] + (float)bc[3]);
    acc = __builtin_amdgcn_mfma_f32_16x16x32_f16(aQ0, kb0, z, 0, 0, 0);
    acc = __builtin_amdgcn_mfma_f32_16x16x32_f16(aQ1, kb1, acc, 0, 0, 0);
    ls0 += fexp2(acc[0] + (float)bc[4]);
    ls1 += fexp2(acc[1] + (float)bc[5]);
    ls2 += fexp2(acc[2] + (float)bc[6]);
    ls3 += fexp2(acc[3] + (float)bc[7]);
    ka0 = na0; ka1 = na1; kb0 = nb0; kb1 = nb1;
#pragma unroll
    for (int i = 0; i < 8; ++i) bc[i] = bn[i];
  }
#pragma unroll
  for (int m = 1; m < 16; m <<= 1) {
    ls0 += __shfl_xor(ls0, m, 64);
    ls1 += __shfl_xor(ls1, m, 64);
    ls2 += __shfl_xor(ls2, m, 64);
    ls3 += __shfl_xor(ls3, m, 64);
  }
  float iv0 = frcp(ls0), iv1 = frcp(ls1), iv2 = frcp(ls2), iv3 = frcp(ls3);

  // ---- pass 2: recompute S'; P staged in f32 LDS; full-line attn stores; PV ----
  __shared__ float pf[4][16][33];        // [wave][q-local][kv-local], pitch 33
  f4 ca0 = {0.f,0.f,0.f,0.f}, ca1 = {0.f,0.f,0.f,0.f};
  f4 ca2 = {0.f,0.f,0.f,0.f}, ca3 = {0.f,0.f,0.f,0.f};
  float* attnw = attn + ((long)bh * NN + q0) * NN;
  int sr = l >> 3, sc = (l & 7) * 4;     // store mapping: 8 rows x 128B per inst
  {
    const _Float16* kp = Kb + (long)s * DK + 8 * g;
    ka0 = *reinterpret_cast<const h8*>(kp);
    ka1 = *reinterpret_cast<const h8*>(kp + 32);
    const _Float16* kq = Kb + (long)(16 + s) * DK + 8 * g;
    kb0 = *reinterpret_cast<const h8*>(kq);
    kb1 = *reinterpret_cast<const h8*>(kq + 32);
    bc[0] = br0[0];  bc[1] = br1[0];  bc[2] = br2[0];  bc[3] = br3[0];
    bc[4] = br0[16]; bc[5] = br1[16]; bc[6] = br2[16]; bc[7] = br3[16];
  }
  for (int c0 = 0; c0 < NN; c0 += 32) {
    int cn = (c0 + 32) & (NN - 1);
    const _Float16* kp = Kb + (long)(cn + s) * DK + 8 * g;
    na0 = *reinterpret_cast<const h8*>(kp);
    na1 = *reinterpret_cast<const h8*>(kp + 32);
    const _Float16* kq = Kb + (long)(cn + 16 + s) * DK + 8 * g;
    nb0 = *reinterpret_cast<const h8*>(kq);
    nb1 = *reinterpret_cast<const h8*>(kq + 32);
    bn[0] = br0[cn];      bn[1] = br1[cn];      bn[2] = br2[cn];      bn[3] = br3[cn];
    bn[4] = br0[cn + 16]; bn[5] = br1[cn + 16]; bn[6] = br2[cn + 16]; bn[7] = br3[cn + 16];
    const _Float16* vp = Vb + (long)s * NN + c0 + 8 * g;
    h8 bv0 = *reinterpret_cast<const h8*>(vp);
    h8 bv1 = *reinterpret_cast<const h8*>(vp + 16 * NN);
    h8 bv2 = *reinterpret_cast<const h8*>(vp + 32 * NN);
    h8 bv3 = *reinterpret_cast<const h8*>(vp + 48 * NN);
    f4 z = {0.f, 0.f, 0.f, 0.f};
    // ct = 0: P cols 0-15 of this chunk
    f4 acc = __builtin_amdgcn_mfma_f32_16x16x32_f16(aQ0, ka0, z, 0, 0, 0);
    acc = __builtin_amdgcn_mfma_f32_16x16x32_f16(aQ1, ka1, acc, 0, 0, 0);
    pf[w][4 * g + 0][s] = fexp2(acc[0] + (float)bc[0]) * iv0;
    pf[w][4 * g + 1][s] = fexp2(acc[1] + (float)bc[1]) * iv1;
    pf[w][4 * g + 2][s] = fexp2(acc[2] + (float)bc[2]) * iv2;
    pf[w][4 * g + 3][s] = fexp2(acc[3] + (float)bc[3]) * iv3;
    // ct = 1: P cols 16-31
    acc = __builtin_amdgcn_mfma_f32_16x16x32_f16(aQ0, kb0, z, 0, 0, 0);
    acc = __builtin_amdgcn_mfma_f32_16x16x32_f16(aQ1, kb1, acc, 0, 0, 0);
    pf[w][4 * g + 0][16 + s] = fexp2(acc[0] + (float)bc[4]) * iv0;
    pf[w][4 * g + 1][16 + s] = fexp2(acc[1] + (float)bc[5]) * iv1;
    pf[w][4 * g + 2][16 + s] = fexp2(acc[2] + (float)bc[6]) * iv2;
    pf[w][4 * g + 3][16 + s] = fexp2(acc[3] + (float)bc[7]) * iv3;
    // attn store: 2 insts, each 8 rows x 128B full lines
    f4 row0 = *reinterpret_cast<const f4*>(&pf[w][sr][sc]);
    f4 row1 = *reinterpret_cast<const f4*>(&pf[w][sr + 8][sc]);
    *reinterpret_cast<f4*>(attnw + (long)sr * NN + c0 + sc) = row0;
    *reinterpret_cast<f4*>(attnw + (long)(sr + 8) * NN + c0 + sc) = row1;
    // PV: A-frag of P from pf (rows s, cols 8g..8g+7), conflict-free reads
    f4 pa = *reinterpret_cast<const f4*>(&pf[w][s][8 * g]);
    f4 pb4 = *reinterpret_cast<const f4*>(&pf[w][s][8 * g + 4]);
    union { h8 v; h2 q[4]; } up;
    up.q[0] = pkrtz(pa[0], pa[1]);  up.q[1] = pkrtz(pa[2], pa[3]);
    up.q[2] = pkrtz(pb4[0], pb4[1]); up.q[3] = pkrtz(pb4[2], pb4[3]);
    h8 aP = up.v;
    ca0 = __builtin_amdgcn_mfma_f32_16x16x32_f16(aP, bv0, ca0, 0, 0, 0);
    ca1 = __builtin_amdgcn_mfma_f32_16x16x32_f16(aP, bv1, ca1, 0, 0, 0);
    ca2 = __builtin_amdgcn_mfma_f32_16x16x32_f16(aP, bv2, ca2, 0, 0, 0);
    ca3 = __builtin_amdgcn_mfma_f32_16x16x32_f16(aP, bv3, ca3, 0, 0, 0);
    ka0 = na0; ka1 = na1; kb0 = nb0; kb1 = nb1;
#pragma unroll
    for (int i = 0; i < 8; ++i) bc[i] = bn[i];
  }
  float* cw = ctx + ((long)bh * NN + q0) * DK;
#pragma unroll
  for (int j = 0; j < 4; ++j) {
    cw[(4 * g + j) * DK + 0  + s] = ca0[j];
    cw[(4 * g + j) * DK + 16 + s] = ca1[j];
    cw[(4 * g + j) * DK + 32 + s] = ca2[j];
    cw[(4 * g + j) * DK + 48 + s] = ca3[j];
  }
}

extern "C" void kernel_launch(void* const* d_in, const int* in_sizes, int n_in,
                              void* d_out, int out_size, void* d_ws, size_t ws_size,
                              hipStream_t stream) {
  const float* Q = (const float*)d_in[0];
  const float* K = (const float*)d_in[1];
  const float* V = (const float*)d_in[2];
  const void* mask = d_in[3];
  const float* edge = (const float*)d_in[4];
  const float* W1 = (const float*)d_in[5];
  const float* b1 = (const float*)d_in[6];
  const float* W2 = (const float*)d_in[7];
  const float* b2 = (const float*)d_in[8];
  float* ctx = (float*)d_out;
  float* attn = ctx + QSZ;                  // outputs: context then attn
  char* ws = (char*)d_ws;
  if (ws_size < WS_NEED) return;
  _Float16* Qh = (_Float16*)(ws + OFF_QH);
  _Float16* Kh = (_Float16*)(ws + OFF_KH);
  _Float16* Vt = (_Float16*)(ws + OFF_VT);
  _Float16* biasM = (_Float16*)(ws + OFF_BIAS);
  int* flag = (int*)(ws + OFF_FLAG);

  k_detect<<<1, 256, 0, stream>>>((const unsigned char*)mask, flag);
  k_prep_qk<<<8192, 256, 0, stream>>>(Q, K, Qh, Kh);
  k_prep_vt<<<1024, 256, 0, stream>>>(V, Vt);
  k_bias<<<8192, 256, 0, stream>>>(edge, mask, W1, b1, W2, b2, flag, biasM);
  k_attn<<<1024, 256, 0, stream>>>(Qh, Kh, Vt, biasM, ctx, attn);
}

// Round 11
// 306.892 us; speedup vs baseline: 1.4178x; 1.2448x over previous
//
#include <hip/hip_runtime.h>
#include <stdint.h>

// Problem constants
constexpr int NB = 8, NH = 8, NN = 1024, DK = 64, ED = 16;
constexpr long QSZ = (long)NB * NH * NN * DK;       // 4,194,304

typedef _Float16 h8 __attribute__((ext_vector_type(8)));
typedef _Float16 h4 __attribute__((ext_vector_type(4)));
typedef _Float16 h2 __attribute__((ext_vector_type(2)));
typedef float f4 __attribute__((ext_vector_type(4)));
typedef float fv16 __attribute__((ext_vector_type(16)));

// ws layout (bytes)
constexpr size_t OFF_QH = 0;                         // 8 MiB fp16 (pre-scaled by 0.125*log2e)
constexpr size_t OFF_KH = 8388608;                   // 8 MiB fp16
constexpr size_t OFF_VT = 16777216;                  // 8 MiB fp16 (transposed [bh][d][k])
constexpr size_t OFF_BIAS = 25165824;                // 16 MiB fp16 (bias*log2e, masked=-30000)
constexpr size_t OFF_FLAG = 58720256;                // 4 B
constexpr size_t WS_NEED = OFF_FLAG + 4;

constexpr float LG2E = 1.4426950408889634f;          // log2(e)
constexpr float C2 = 2.8853900817779268f;            // 2*log2(e)
constexpr float QS = 0.125f * LG2E;                  // fold 1/sqrt(dk) and log2e into Q

static __device__ __forceinline__ float fexp2(float x) {
  float r; asm("v_exp_f32 %0, %1" : "=v"(r) : "v"(x)); return r;
}
static __device__ __forceinline__ float frcp(float x) {
  float r; asm("v_rcp_f32 %0, %1" : "=v"(r) : "v"(x)); return r;
}
static __device__ __forceinline__ h2 pkrtz(float a, float b) {
  return __builtin_bit_cast(h2, __builtin_amdgcn_cvt_pkrtz(a, b));
}
// async global->LDS, 16B per lane; lptr must be WAVE-UNIFORM (HW scatters lane i to lptr + i*16)
static __device__ __forceinline__ void gl16(const void* g, void* l) {
  __builtin_amdgcn_global_load_lds(
      (const __attribute__((address_space(1))) uint32_t*)g,
      (__attribute__((address_space(3))) uint32_t*)l, 16, 0, 0);
}

// ---------- prep: Q (x 0.125*log2e) and K -> fp16, same layout ----------
__global__ __launch_bounds__(256) void k_prep_qk(
    const float* __restrict__ Q, const float* __restrict__ K,
    _Float16* __restrict__ Qh, _Float16* __restrict__ Kh) {
  int i = blockIdx.x * 256 + threadIdx.x;
  const int n4 = (int)(QSZ / 4);
  if (i < n4) {
    float4 v = reinterpret_cast<const float4*>(Q)[i];
    h4 o; o[0] = (_Float16)(v.x * QS); o[1] = (_Float16)(v.y * QS);
          o[2] = (_Float16)(v.z * QS); o[3] = (_Float16)(v.w * QS);
    reinterpret_cast<h4*>(Qh)[i] = o;
  } else {
    int j = i - n4;
    float4 v = reinterpret_cast<const float4*>(K)[j];
    h4 o; o[0] = (_Float16)v.x; o[1] = (_Float16)v.y;
          o[2] = (_Float16)v.z; o[3] = (_Float16)v.w;
    reinterpret_cast<h4*>(Kh)[j] = o;
  }
}

// ---------- prep: V [bh][k][d] fp32 -> Vt [bh][d][k] fp16 ----------
__global__ __launch_bounds__(256) void k_prep_vt(
    const float* __restrict__ V, _Float16* __restrict__ Vt) {
  int wid = (blockIdx.x * 256 + threadIdx.x) >> 6;   // 4096 waves
  int lane = threadIdx.x & 63;
  int bh = wid >> 6;
  int k0 = (wid & 63) << 4;
  const float* Vb = V + (long)bh * NN * DK;
  _Float16* Vo = Vt + (long)bh * DK * NN + (long)lane * NN + k0;
  h8 p0, p1;
#pragma unroll
  for (int i = 0; i < 16; ++i) {
    float v = Vb[(long)(k0 + i) * DK + lane];
    if (i < 8) p0[i] = (_Float16)v; else p1[i - 8] = (_Float16)v;
  }
  *reinterpret_cast<h8*>(Vo) = p0;
  *reinterpret_cast<h8*>(Vo + 8) = p1;
}

// ---------- detect mask element width (bool bytes vs int32); no pre-zero needed ----------
__global__ void k_detect(const unsigned char* __restrict__ m, int* __restrict__ flag) {
  __shared__ int sh[4];
  int t = threadIdx.x;
  int any = 0;
  for (int i = t; i < 4096; i += 256)
    if ((i & 3) && m[i]) any = 1;          // int32 0/1 never has nonzero at %4!=0
  unsigned long long b = __ballot(any);
  if ((t & 63) == 0) sh[t >> 6] = (b != 0) ? 1 : 0;
  __syncthreads();
  if (t == 0) flag[0] = sh[0] | sh[1] | sh[2] | sh[3];
}

// ---------- edge-bias MLP + mask fold (unchanged from R8/R10) ----------
__global__ __launch_bounds__(256, 3) void k_bias(
    const float* __restrict__ edge, const void* __restrict__ maskp,
    const float* __restrict__ W1, const float* __restrict__ b1,
    const float* __restrict__ W2, const float* __restrict__ b2,
    const int* __restrict__ flag, _Float16* __restrict__ biasM) {
  int bq = blockIdx.x;
  int w = threadIdx.x >> 6, l = threadIdx.x & 63;
  int h = l >> 5, c31 = l & 31;
  bool isbool = (*flag != 0);
  h8 aw0, aw1;
#pragma unroll
  for (int j = 0; j < 8; ++j) {
    aw0[j] = (_Float16)(W1[(8 * h + j) * 64 + 0  + c31] * C2);
    aw1[j] = (_Float16)(W1[(8 * h + j) * 64 + 32 + c31] * C2);
  }
  h2 pb[16], pw[16];
  float sw = 0.f;
#pragma unroll
  for (int r = 0; r < 16; ++r) {
    int dr = (r & 3) + 8 * (r >> 2) + 4 * h;
    float b0 = b1[dr] * C2, b1v = b1[32 + dr] * C2;
    float w0 = W2[dr], w1v = W2[32 + dr];
    pb[r] = pkrtz(b0, b1v);
    pw[r] = pkrtz(w0, w1v);
    sw += w0 + w1v;
  }
  sw += __shfl_xor(sw, 32, 64);
  float base = (sw + b2[0]) * LG2E;

  const float* erow = edge + (long)bq * NN * ED;
  const float4* erow4 = reinterpret_cast<const float4*>(erow);
  _Float16* orow = biasM + (long)bq * NN;
  const int* mrowi = (const int*)maskp + (long)bq * NN;
  const unsigned char* mrowb = (const unsigned char*)maskp + (long)bq * NN;

  fv16 z;
#pragma unroll
  for (int r = 0; r < 16; ++r) z[r] = 0.f;

  int kbase = w * 256;
  float4 e0a = erow4[(kbase + c31) * 4 + 2 * h];
  float4 e0b = erow4[(kbase + c31) * 4 + 2 * h + 1];
  float4 e1a = erow4[(kbase + 32 + c31) * 4 + 2 * h];
  float4 e1b = erow4[(kbase + 32 + c31) * 4 + 2 * h + 1];
#pragma unroll
  for (int p = 0; p < 4; ++p) {
    float4 n0a, n0b, n1a, n1b;
    if (p < 3) {
      int nb = kbase + 64;
      n0a = erow4[(nb + c31) * 4 + 2 * h];
      n0b = erow4[(nb + c31) * 4 + 2 * h + 1];
      n1a = erow4[(nb + 32 + c31) * 4 + 2 * h];
      n1b = erow4[(nb + 32 + c31) * 4 + 2 * h + 1];
    }
    union { h8 v; h2 q[4]; } u0, u1;
    u0.q[0] = pkrtz(e0a.x, e0a.y); u0.q[1] = pkrtz(e0a.z, e0a.w);
    u0.q[2] = pkrtz(e0b.x, e0b.y); u0.q[3] = pkrtz(e0b.z, e0b.w);
    u1.q[0] = pkrtz(e1a.x, e1a.y); u1.q[1] = pkrtz(e1a.z, e1a.w);
    u1.q[2] = pkrtz(e1b.x, e1b.y); u1.q[3] = pkrtz(e1b.z, e1b.w);
    float a00 = 0.f, a01 = 0.f, a10 = 0.f, a11 = 0.f;
    {
      fv16 hA0 = __builtin_amdgcn_mfma_f32_32x32x16_f16(aw0, u0.v, z, 0, 0, 0);
      fv16 hA1 = __builtin_amdgcn_mfma_f32_32x32x16_f16(aw0, u1.v, z, 0, 0, 0);
#pragma unroll
      for (int r = 0; r < 16; ++r) {
        float bb = (float)pb[r][0];
        float ww = (float)pw[r][0];
        if (r & 1) {
          a01 = fmaf(ww, frcp(fexp2(hA0[r] + bb) + 1.f), a01);
          a11 = fmaf(ww, frcp(fexp2(hA1[r] + bb) + 1.f), a11);
        } else {
          a00 = fmaf(ww, frcp(fexp2(hA0[r] + bb) + 1.f), a00);
          a10 = fmaf(ww, frcp(fexp2(hA1[r] + bb) + 1.f), a10);
        }
      }
    }
    {
      fv16 hB0 = __builtin_amdgcn_mfma_f32_32x32x16_f16(aw1, u0.v, z, 0, 0, 0);
      fv16 hB1 = __builtin_amdgcn_mfma_f32_32x32x16_f16(aw1, u1.v, z, 0, 0, 0);
#pragma unroll
      for (int r = 0; r < 16; ++r) {
        float bb = (float)pb[r][1];
        float ww = (float)pw[r][1];
        if (r & 1) {
          a01 = fmaf(ww, frcp(fexp2(hB0[r] + bb) + 1.f), a01);
          a11 = fmaf(ww, frcp(fexp2(hB1[r] + bb) + 1.f), a11);
        } else {
          a00 = fmaf(ww, frcp(fexp2(hB0[r] + bb) + 1.f), a00);
          a10 = fmaf(ww, frcp(fexp2(hB1[r] + bb) + 1.f), a10);
        }
      }
    }
    float p0 = a00 + a01;
    float p1 = a10 + a11;
    p0 += __shfl_xor(p0, 32, 64);
    p1 += __shfl_xor(p1, 32, 64);
    float part = h ? p1 : p0;
    int idx = kbase + 32 * h + c31;
    int m = isbool ? (int)mrowb[idx] : mrowi[idx];
    orow[idx] = m ? (_Float16)(-30000.0f) : (_Float16)fmaf(-C2, part, base);
    e0a = n0a; e0b = n0b; e1a = n1a; e1b = n1b;
    kbase += 64;
  }
}

// ---------- fused attention: double-buffered global_load_lds staging of K/V/bias ----------
// All 4 waves share the K/V tiles (were loaded 4x redundantly before).
// K tile: [32 kv][64 d] fp16, 128B rows, XOR-swizzled (byte ^= (row&7)<<4) via
// pre-swizzled GLOBAL source + linear LDS dest (rule: both-sides-or-neither).
// V tile: [64 d][32 kv] fp16, 64B rows, swizzle (row&3)<<4. Bias tile: [64 q][32 kv] linear.
__global__ __launch_bounds__(256) void k_attn(
    const _Float16* __restrict__ Qh, const _Float16* __restrict__ Kh,
    const _Float16* __restrict__ Vt, const _Float16* __restrict__ biasH,
    float* __restrict__ ctx, float* __restrict__ attn) {
  int bid = blockIdx.x;
  int b = bid & 7;           // XCD-pinned batch
  int t_ = bid >> 3;
  int hh = t_ & 7;
  int qb = t_ >> 3;
  int bh = b * 8 + hh;
  int tid = threadIdx.x;
  int w = tid >> 6, l = tid & 63;
  int g = l >> 4, s = l & 15;
  int q0 = qb * 64 + w * 16;

  const _Float16* Qw = Qh + ((long)bh * NN + q0) * DK;
  const char* Kbase = (const char*)(Kh + (long)bh * NN * DK);             // 128B rows
  const char* Vbase = (const char*)(Vt + (long)bh * DK * NN);             // 2048B rows
  const char* Bbase = (const char*)(biasH + (long)b * NN * NN + (long)(qb * 64) * NN); // 2048B rows
  h8 aQ0 = *reinterpret_cast<const h8*>(Qw + s * DK + 8 * g);
  h8 aQ1 = *reinterpret_cast<const h8*>(Qw + s * DK + 32 + 8 * g);
  const f4 z4 = {0.f, 0.f, 0.f, 0.f};

  __shared__ __align__(16) _Float16 kt[2][32 * 64];
  __shared__ __align__(16) _Float16 vt2[2][64 * 32];
  __shared__ __align__(16) _Float16 bt[2][64 * 32];
  __shared__ float pf[4][16][33];

  // staging geometry (thread t stages 16B; LDS dest is wave-uniform base, HW scatters lane*16)
  int krow = tid >> 3;                                        // 0..31
  int kcol = ((tid & 7) * 16) ^ ((krow & 7) << 4);            // pre-swizzled source col
  int vrow = tid >> 2;                                        // 0..63
  int vcol = ((tid & 3) * 16) ^ ((vrow & 3) << 4);
  int brow = tid >> 2;                                        // 0..63 (q_local)
  int bcol = (tid & 3) * 16;                                  // linear
  int wofs = w << 10;                                         // wave's 1 KiB quarter

  // swizzled read offsets
  int ksw = (s & 7) << 4;
  int vswz = (s & 3) << 4;

#define STK(buf, c0) gl16(Kbase + (long)((c0) + krow) * 128 + kcol, (char*)kt[buf] + wofs)
#define STV(buf, c0) gl16(Vbase + (long)vrow * 2048 + (c0) * 2 + vcol, (char*)vt2[buf] + wofs)
#define STB(buf, c0) gl16(Bbase + (long)brow * 2048 + (c0) * 2 + bcol, (char*)bt[buf] + wofs)
#define BIAS(buf, j, kvl) ((float)*(const _Float16*)((const char*)bt[buf] + (w * 16 + 4 * g + (j)) * 64 + (kvl) * 2))

  // ---- pass 1: row sums of exp2(S') ----
  float ls0 = 0.f, ls1 = 0.f, ls2 = 0.f, ls3 = 0.f;
  STK(0, 0); STB(0, 0);
  {
    int buf = 0;
    for (int c0 = 0; c0 < NN; c0 += 32, buf ^= 1) {
      __syncthreads();                       // drains this wave's gload_lds; barrier = tile ready
      if (c0 + 32 < NN) { STK(buf ^ 1, c0 + 32); STB(buf ^ 1, c0 + 32); }
      const char* kbuf = (const char*)kt[buf];
      // half 0: kv rows s
      h8 k0 = *(const h8*)(kbuf + s * 128 + ((16 * g) ^ ksw));
      h8 k1 = *(const h8*)(kbuf + s * 128 + ((64 + 16 * g) ^ ksw));
      f4 acc = __builtin_amdgcn_mfma_f32_16x16x32_f16(aQ0, k0, z4, 0, 0, 0);
      acc = __builtin_amdgcn_mfma_f32_16x16x32_f16(aQ1, k1, acc, 0, 0, 0);
      ls0 += fexp2(acc[0] + BIAS(buf, 0, s));
      ls1 += fexp2(acc[1] + BIAS(buf, 1, s));
      ls2 += fexp2(acc[2] + BIAS(buf, 2, s));
      ls3 += fexp2(acc[3] + BIAS(buf, 3, s));
      // half 1: kv rows 16+s
      k0 = *(const h8*)(kbuf + (16 + s) * 128 + ((16 * g) ^ ksw));
      k1 = *(const h8*)(kbuf + (16 + s) * 128 + ((64 + 16 * g) ^ ksw));
      acc = __builtin_amdgcn_mfma_f32_16x16x32_f16(aQ0, k0, z4, 0, 0, 0);
      acc = __builtin_amdgcn_mfma_f32_16x16x32_f16(aQ1, k1, acc, 0, 0, 0);
      ls0 += fexp2(acc[0] + BIAS(buf, 0, 16 + s));
      ls1 += fexp2(acc[1] + BIAS(buf, 1, 16 + s));
      ls2 += fexp2(acc[2] + BIAS(buf, 2, 16 + s));
      ls3 += fexp2(acc[3] + BIAS(buf, 3, 16 + s));
    }
  }
#pragma unroll
  for (int m = 1; m < 16; m <<= 1) {
    ls0 += __shfl_xor(ls0, m, 64);
    ls1 += __shfl_xor(ls1, m, 64);
    ls2 += __shfl_xor(ls2, m, 64);
    ls3 += __shfl_xor(ls3, m, 64);
  }
  float iv0 = frcp(ls0), iv1 = frcp(ls1), iv2 = frcp(ls2), iv3 = frcp(ls3);

  // ---- pass 2: recompute S'; P via f32 LDS; full-line attn stores; PV from LDS V ----
  f4 ca0 = {0.f,0.f,0.f,0.f}, ca1 = {0.f,0.f,0.f,0.f};
  f4 ca2 = {0.f,0.f,0.f,0.f}, ca3 = {0.f,0.f,0.f,0.f};
  float* attnw = attn + ((long)bh * NN + q0) * NN;
  int sr = l >> 3, sc = (l & 7) * 4;     // attn store mapping: 8 rows x 128B full lines
  __syncthreads();                        // all waves done with pass-1 buffers
  STK(0, 0); STV(0, 0); STB(0, 0);
  {
    int buf = 0;
    for (int c0 = 0; c0 < NN; c0 += 32, buf ^= 1) {
      __syncthreads();
      if (c0 + 32 < NN) { STK(buf ^ 1, c0 + 32); STV(buf ^ 1, c0 + 32); STB(buf ^ 1, c0 + 32); }
      const char* kbuf = (const char*)kt[buf];
      const char* vbuf = (const char*)vt2[buf];
      // ct = 0
      h8 k0 = *(const h8*)(kbuf + s * 128 + ((16 * g) ^ ksw));
      h8 k1 = *(const h8*)(kbuf + s * 128 + ((64 + 16 * g) ^ ksw));
      f4 acc = __builtin_amdgcn_mfma_f32_16x16x32_f16(aQ0, k0, z4, 0, 0, 0);
      acc = __builtin_amdgcn_mfma_f32_16x16x32_f16(aQ1, k1, acc, 0, 0, 0);
      pf[w][4 * g + 0][s] = fexp2(acc[0] + BIAS(buf, 0, s)) * iv0;
      pf[w][4 * g + 1][s] = fexp2(acc[1] + BIAS(buf, 1, s)) * iv1;
      pf[w][4 * g + 2][s] = fexp2(acc[2] + BIAS(buf, 2, s)) * iv2;
      pf[w][4 * g + 3][s] = fexp2(acc[3] + BIAS(buf, 3, s)) * iv3;
      // ct = 1
      k0 = *(const h8*)(kbuf + (16 + s) * 128 + ((16 * g) ^ ksw));
      k1 = *(const h8*)(kbuf + (16 + s) * 128 + ((64 + 16 * g) ^ ksw));
      acc = __builtin_amdgcn_mfma_f32_16x16x32_f16(aQ0, k0, z4, 0, 0, 0);
      acc = __builtin_amdgcn_mfma_f32_16x16x32_f16(aQ1, k1, acc, 0, 0, 0);
      pf[w][4 * g + 0][16 + s] = fexp2(acc[0] + BIAS(buf, 0, 16 + s)) * iv0;
      pf[w][4 * g + 1][16 + s] = fexp2(acc[1] + BIAS(buf, 1, 16 + s)) * iv1;
      pf[w][4 * g + 2][16 + s] = fexp2(acc[2] + BIAS(buf, 2, 16 + s)) * iv2;
      pf[w][4 * g + 3][16 + s] = fexp2(acc[3] + BIAS(buf, 3, 16 + s)) * iv3;
      // attn store: 2 insts, each 8 rows x 128B full lines
      f4 row0 = *reinterpret_cast<const f4*>(&pf[w][sr][sc]);
      f4 row1 = *reinterpret_cast<const f4*>(&pf[w][sr + 8][sc]);
      *reinterpret_cast<f4*>(attnw + (long)sr * NN + c0 + sc) = row0;
      *reinterpret_cast<f4*>(attnw + (long)(sr + 8) * NN + c0 + sc) = row1;
      // PV: P A-frag from pf; V B-frags from swizzled LDS tile
      f4 pa = *reinterpret_cast<const f4*>(&pf[w][s][8 * g]);
      f4 pb4 = *reinterpret_cast<const f4*>(&pf[w][s][8 * g + 4]);
      union { h8 v; h2 q[4]; } up;
      up.q[0] = pkrtz(pa[0], pa[1]);  up.q[1] = pkrtz(pa[2], pa[3]);
      up.q[2] = pkrtz(pb4[0], pb4[1]); up.q[3] = pkrtz(pb4[2], pb4[3]);
      h8 aP = up.v;
      h8 bv0 = *(const h8*)(vbuf + (s)      * 64 + ((16 * g) ^ vswz));
      h8 bv1 = *(const h8*)(vbuf + (16 + s) * 64 + ((16 * g) ^ vswz));
      h8 bv2 = *(const h8*)(vbuf + (32 + s) * 64 + ((16 * g) ^ vswz));
      h8 bv3 = *(const h8*)(vbuf + (48 + s) * 64 + ((16 * g) ^ vswz));
      ca0 = __builtin_amdgcn_mfma_f32_16x16x32_f16(aP, bv0, ca0, 0, 0, 0);
      ca1 = __builtin_amdgcn_mfma_f32_16x16x32_f16(aP, bv1, ca1, 0, 0, 0);
      ca2 = __builtin_amdgcn_mfma_f32_16x16x32_f16(aP, bv2, ca2, 0, 0, 0);
      ca3 = __builtin_amdgcn_mfma_f32_16x16x32_f16(aP, bv3, ca3, 0, 0, 0);
    }
  }
  float* cw = ctx + ((long)bh * NN + q0) * DK;
#pragma unroll
  for (int j = 0; j < 4; ++j) {
    cw[(4 * g + j) * DK + 0  + s] = ca0[j];
    cw[(4 * g + j) * DK + 16 + s] = ca1[j];
    cw[(4 * g + j) * DK + 32 + s] = ca2[j];
    cw[(4 * g + j) * DK + 48 + s] = ca3[j];
  }
#undef STK
#undef STV
#undef STB
#undef BIAS
}

extern "C" void kernel_launch(void* const* d_in, const int* in_sizes, int n_in,
                              void* d_out, int out_size, void* d_ws, size_t ws_size,
                              hipStream_t stream) {
  const float* Q = (const float*)d_in[0];
  const float* K = (const float*)d_in[1];
  const float* V = (const float*)d_in[2];
  const void* mask = d_in[3];
  const float* edge = (const float*)d_in[4];
  const float* W1 = (const float*)d_in[5];
  const float* b1 = (const float*)d_in[6];
  const float* W2 = (const float*)d_in[7];
  const float* b2 = (const float*)d_in[8];
  float* ctx = (float*)d_out;
  float* attn = ctx + QSZ;                  // outputs: context then attn
  char* ws = (char*)d_ws;
  if (ws_size < WS_NEED) return;
  _Float16* Qh = (_Float16*)(ws + OFF_QH);
  _Float16* Kh = (_Float16*)(ws + OFF_KH);
  _Float16* Vt = (_Float16*)(ws + OFF_VT);
  _Float16* biasM = (_Float16*)(ws + OFF_BIAS);
  int* flag = (int*)(ws + OFF_FLAG);

  k_detect<<<1, 256, 0, stream>>>((const unsigned char*)mask, flag);
  k_prep_qk<<<8192, 256, 0, stream>>>(Q, K, Qh, Kh);
  k_prep_vt<<<1024, 256, 0, stream>>>(V, Vt);
  k_bias<<<8192, 256, 0, stream>>>(edge, mask, W1, b1, W2, b2, flag, biasM);
  k_attn<<<1024, 256, 0, stream>>>(Qh, Kh, Vt, biasM, ctx, attn);
}

// Round 12
// 302.991 us; speedup vs baseline: 1.4361x; 1.0129x over previous
//
#include <hip/hip_runtime.h>
#include <stdint.h>

// Problem constants
constexpr int NB = 8, NH = 8, NN = 1024, DK = 64, ED = 16;
constexpr long QSZ = (long)NB * NH * NN * DK;       // 4,194,304

typedef _Float16 h8 __attribute__((ext_vector_type(8)));
typedef _Float16 h4 __attribute__((ext_vector_type(4)));
typedef _Float16 h2 __attribute__((ext_vector_type(2)));
typedef float f4 __attribute__((ext_vector_type(4)));
typedef float fv16 __attribute__((ext_vector_type(16)));

// ws layout (bytes)
constexpr size_t OFF_QH = 0;                         // 8 MiB fp16 (pre-scaled by 0.125*log2e)
constexpr size_t OFF_KH = 8388608;                   // 8 MiB fp16
constexpr size_t OFF_VT = 16777216;                  // 8 MiB fp16 (transposed [bh][d][k])
constexpr size_t OFF_BIAS = 25165824;                // 16 MiB fp16 (bias*log2e, masked=-30000)
constexpr size_t OFF_FLAG = 58720256;                // 4 B
constexpr size_t WS_NEED = OFF_FLAG + 4;

constexpr float LG2E = 1.4426950408889634f;          // log2(e)
constexpr float C2 = 2.8853900817779268f;            // 2*log2(e)
constexpr float QS = 0.125f * LG2E;                  // fold 1/sqrt(dk) and log2e into Q

static __device__ __forceinline__ float fexp2(float x) {
  float r; asm("v_exp_f32 %0, %1" : "=v"(r) : "v"(x)); return r;
}
static __device__ __forceinline__ float frcp(float x) {
  float r; asm("v_rcp_f32 %0, %1" : "=v"(r) : "v"(x)); return r;
}
static __device__ __forceinline__ h2 pkrtz(float a, float b) {
  return __builtin_bit_cast(h2, __builtin_amdgcn_cvt_pkrtz(a, b));
}
// async global->LDS, 16B per lane; lptr must be WAVE-UNIFORM (HW scatters lane i to lptr + i*16)
static __device__ __forceinline__ void gl16(const void* g, void* l) {
  __builtin_amdgcn_global_load_lds(
      (const __attribute__((address_space(1))) uint32_t*)g,
      (__attribute__((address_space(3))) uint32_t*)l, 16, 0, 0);
}

// ---------- merged prep: Q (x 0.125*log2e) + K -> fp16; V -> Vt fp16 transposed ----------
__global__ __launch_bounds__(256) void k_prep(
    const float* __restrict__ Q, const float* __restrict__ K, const float* __restrict__ V,
    _Float16* __restrict__ Qh, _Float16* __restrict__ Kh, _Float16* __restrict__ Vt) {
  int bid = blockIdx.x;
  if (bid < 8192) {
    int i = bid * 256 + threadIdx.x;
    const int n4 = (int)(QSZ / 4);
    if (i < n4) {
      float4 v = reinterpret_cast<const float4*>(Q)[i];
      h4 o; o[0] = (_Float16)(v.x * QS); o[1] = (_Float16)(v.y * QS);
            o[2] = (_Float16)(v.z * QS); o[3] = (_Float16)(v.w * QS);
      reinterpret_cast<h4*>(Qh)[i] = o;
    } else {
      int j = i - n4;
      float4 v = reinterpret_cast<const float4*>(K)[j];
      h4 o; o[0] = (_Float16)v.x; o[1] = (_Float16)v.y;
            o[2] = (_Float16)v.z; o[3] = (_Float16)v.w;
      reinterpret_cast<h4*>(Kh)[j] = o;
    }
  } else {
    int wid = ((bid - 8192) * 256 + threadIdx.x) >> 6;
    int lane = threadIdx.x & 63;
    int bh = wid >> 6;
    int k0 = (wid & 63) << 4;
    const float* Vb = V + (long)bh * NN * DK;
    _Float16* Vo = Vt + (long)bh * DK * NN + (long)lane * NN + k0;
    h8 p0, p1;
#pragma unroll
    for (int i = 0; i < 16; ++i) {
      float v = Vb[(long)(k0 + i) * DK + lane];
      if (i < 8) p0[i] = (_Float16)v; else p1[i - 8] = (_Float16)v;
    }
    *reinterpret_cast<h8*>(Vo) = p0;
    *reinterpret_cast<h8*>(Vo + 8) = p1;
  }
}

// ---------- detect mask element width (bool bytes vs int32); no pre-zero needed ----------
__global__ void k_detect(const unsigned char* __restrict__ m, int* __restrict__ flag) {
  __shared__ int sh[4];
  int t = threadIdx.x;
  int any = 0;
  for (int i = t; i < 4096; i += 256)
    if ((i & 3) && m[i]) any = 1;          // int32 0/1 never has nonzero at %4!=0
  unsigned long long b = __ballot(any);
  if ((t & 63) == 0) sh[t >> 6] = (b != 0) ? 1 : 0;
  __syncthreads();
  if (t == 0) flag[0] = sh[0] | sh[1] | sh[2] | sh[3];
}

// ---------- edge-bias MLP + mask fold: global_load_lds staged edge, zero-VMEM loop ----------
// Per-wave private double-buffered 4KB tiles (64 kv x 64B). Source pre-swizzled with
// col ^= ((row&3)<<4); reads apply the same XOR. Counted vmcnt(4) keeps next tile in flight.
__global__ __launch_bounds__(256, 3) void k_bias(
    const float* __restrict__ edge, const void* __restrict__ maskp,
    const float* __restrict__ W1, const float* __restrict__ b1,
    const float* __restrict__ W2, const float* __restrict__ b2,
    const int* __restrict__ flag, _Float16* __restrict__ biasM) {
  int bq = blockIdx.x;
  int w = threadIdx.x >> 6, l = threadIdx.x & 63;
  int h = l >> 5, c31 = l & 31;
  bool isbool = (*flag != 0);
  h8 aw0, aw1;
#pragma unroll
  for (int j = 0; j < 8; ++j) {
    aw0[j] = (_Float16)(W1[(8 * h + j) * 64 + 0  + c31] * C2);
    aw1[j] = (_Float16)(W1[(8 * h + j) * 64 + 32 + c31] * C2);
  }
  h2 pb[16], pw[16];
  float sw = 0.f;
#pragma unroll
  for (int r = 0; r < 16; ++r) {
    int dr = (r & 3) + 8 * (r >> 2) + 4 * h;
    float b0 = b1[dr] * C2, b1v = b1[32 + dr] * C2;
    float w0 = W2[dr], w1v = W2[32 + dr];
    pb[r] = pkrtz(b0, b1v);
    pw[r] = pkrtz(w0, w1v);
    sw += w0 + w1v;
  }
  sw += __shfl_xor(sw, 32, 64);
  float base = (sw + b2[0]) * LG2E;

  const char* erow_b = (const char*)(edge + (long)bq * NN * ED);  // 64B per kv row
  _Float16* orow = biasM + (long)bq * NN;
  const int* mrowi = (const int*)maskp + (long)bq * NN;
  const unsigned char* mrowb = (const unsigned char*)maskp + (long)bq * NN;

  fv16 z;
#pragma unroll
  for (int r = 0; r < 16; ++r) z[r] = 0.f;

  int kq0 = w * 256;
  // preload mask (keeps the main loop free of non-staging VMEM)
  int m4[4];
#pragma unroll
  for (int p = 0; p < 4; ++p) {
    int idx = kq0 + p * 64 + 32 * h + c31;
    m4[p] = isbool ? (int)mrowb[idx] : mrowi[idx];
  }

  // per-wave double-buffered edge tiles: [wave][buf][64 rows x 64B]
  __shared__ __align__(16) float ebuf[4][2][1024];
  int r4 = l >> 2;                                    // staging row within 16-row issue
  int csw = ((l & 3) * 16) ^ ((r4 & 3) << 4);         // pre-swizzled source col
#define STAGE(buf, p) do { \
    const char* src_ = erow_b + (long)(kq0 + (p) * 64) * 64; \
    char* dst_ = (char*)&ebuf[w][buf][0]; \
    gl16(src_ + (long)(r4) * 64 + csw, dst_); \
    gl16(src_ + (long)(16 + r4) * 64 + csw, dst_ + 1024); \
    gl16(src_ + (long)(32 + r4) * 64 + csw, dst_ + 2048); \
    gl16(src_ + (long)(48 + r4) * 64 + csw, dst_ + 3072); \
  } while (0)

  int sw0 = (c31 & 3) << 4;                           // read-side XOR (rows r and 32+r share it)
  float res[4];
  STAGE(0, 0);
#pragma unroll
  for (int p = 0; p < 4; ++p) {
    if (p < 3) STAGE((p + 1) & 1, p + 1);
    if (p < 3) { asm volatile("s_waitcnt vmcnt(4)" ::: "memory"); }
    else       { asm volatile("s_waitcnt vmcnt(0)" ::: "memory"); }
    const char* tb = (const char*)&ebuf[w][p & 1][0];
    f4 e0a = *(const f4*)(tb + c31 * 64 + ((h * 32) ^ sw0));
    f4 e0b = *(const f4*)(tb + c31 * 64 + ((h * 32 + 16) ^ sw0));
    f4 e1a = *(const f4*)(tb + (32 + c31) * 64 + ((h * 32) ^ sw0));
    f4 e1b = *(const f4*)(tb + (32 + c31) * 64 + ((h * 32 + 16) ^ sw0));
    union { h8 v; h2 q[4]; } u0, u1;
    u0.q[0] = pkrtz(e0a[0], e0a[1]); u0.q[1] = pkrtz(e0a[2], e0a[3]);
    u0.q[2] = pkrtz(e0b[0], e0b[1]); u0.q[3] = pkrtz(e0b[2], e0b[3]);
    u1.q[0] = pkrtz(e1a[0], e1a[1]); u1.q[1] = pkrtz(e1a[2], e1a[3]);
    u1.q[2] = pkrtz(e1b[0], e1b[1]); u1.q[3] = pkrtz(e1b[2], e1b[3]);
    float a00 = 0.f, a01 = 0.f, a10 = 0.f, a11 = 0.f;
    {
      fv16 hA0 = __builtin_amdgcn_mfma_f32_32x32x16_f16(aw0, u0.v, z, 0, 0, 0);
      fv16 hA1 = __builtin_amdgcn_mfma_f32_32x32x16_f16(aw0, u1.v, z, 0, 0, 0);
#pragma unroll
      for (int r = 0; r < 16; ++r) {
        float bb = (float)pb[r][0];
        float ww = (float)pw[r][0];
        if (r & 1) {
          a01 = fmaf(ww, frcp(fexp2(hA0[r] + bb) + 1.f), a01);
          a11 = fmaf(ww, frcp(fexp2(hA1[r] + bb) + 1.f), a11);
        } else {
          a00 = fmaf(ww, frcp(fexp2(hA0[r] + bb) + 1.f), a00);
          a10 = fmaf(ww, frcp(fexp2(hA1[r] + bb) + 1.f), a10);
        }
      }
    }
    {
      fv16 hB0 = __builtin_amdgcn_mfma_f32_32x32x16_f16(aw1, u0.v, z, 0, 0, 0);
      fv16 hB1 = __builtin_amdgcn_mfma_f32_32x32x16_f16(aw1, u1.v, z, 0, 0, 0);
#pragma unroll
      for (int r = 0; r < 16; ++r) {
        float bb = (float)pb[r][1];
        float ww = (float)pw[r][1];
        if (r & 1) {
          a01 = fmaf(ww, frcp(fexp2(hB0[r] + bb) + 1.f), a01);
          a11 = fmaf(ww, frcp(fexp2(hB1[r] + bb) + 1.f), a11);
        } else {
          a00 = fmaf(ww, frcp(fexp2(hB0[r] + bb) + 1.f), a00);
          a10 = fmaf(ww, frcp(fexp2(hB1[r] + bb) + 1.f), a10);
        }
      }
    }
    float p0 = a00 + a01;
    float p1 = a10 + a11;
    p0 += __shfl_xor(p0, 32, 64);
    p1 += __shfl_xor(p1, 32, 64);
    res[p] = h ? p1 : p0;
  }
#undef STAGE
#pragma unroll
  for (int p = 0; p < 4; ++p) {
    int idx = kq0 + p * 64 + 32 * h + c31;
    orow[idx] = m4[p] ? (_Float16)(-30000.0f) : (_Float16)fmaf(-C2, res[p], base);
  }
}

// ---------- fused attention (unchanged from R11 winner) ----------
__global__ __launch_bounds__(256) void k_attn(
    const _Float16* __restrict__ Qh, const _Float16* __restrict__ Kh,
    const _Float16* __restrict__ Vt, const _Float16* __restrict__ biasH,
    float* __restrict__ ctx, float* __restrict__ attn) {
  int bid = blockIdx.x;
  int b = bid & 7;           // XCD-pinned batch
  int t_ = bid >> 3;
  int hh = t_ & 7;
  int qb = t_ >> 3;
  int bh = b * 8 + hh;
  int tid = threadIdx.x;
  int w = tid >> 6, l = tid & 63;
  int g = l >> 4, s = l & 15;
  int q0 = qb * 64 + w * 16;

  const _Float16* Qw = Qh + ((long)bh * NN + q0) * DK;
  const char* Kbase = (const char*)(Kh + (long)bh * NN * DK);             // 128B rows
  const char* Vbase = (const char*)(Vt + (long)bh * DK * NN);             // 2048B rows
  const char* Bbase = (const char*)(biasH + (long)b * NN * NN + (long)(qb * 64) * NN); // 2048B rows
  h8 aQ0 = *reinterpret_cast<const h8*>(Qw + s * DK + 8 * g);
  h8 aQ1 = *reinterpret_cast<const h8*>(Qw + s * DK + 32 + 8 * g);
  const f4 z4 = {0.f, 0.f, 0.f, 0.f};

  __shared__ __align__(16) _Float16 kt[2][32 * 64];
  __shared__ __align__(16) _Float16 vt2[2][64 * 32];
  __shared__ __align__(16) _Float16 bt[2][64 * 32];
  __shared__ float pf[4][16][33];

  int krow = tid >> 3;                                        // 0..31
  int kcol = ((tid & 7) * 16) ^ ((krow & 7) << 4);            // pre-swizzled source col
  int vrow = tid >> 2;                                        // 0..63
  int vcol = ((tid & 3) * 16) ^ ((vrow & 3) << 4);
  int brow = tid >> 2;                                        // 0..63 (q_local)
  int bcol = (tid & 3) * 16;                                  // linear
  int wofs = w << 10;                                         // wave's 1 KiB quarter

  int ksw = (s & 7) << 4;
  int vswz = (s & 3) << 4;

#define STK(buf, c0) gl16(Kbase + (long)((c0) + krow) * 128 + kcol, (char*)kt[buf] + wofs)
#define STV(buf, c0) gl16(Vbase + (long)vrow * 2048 + (c0) * 2 + vcol, (char*)vt2[buf] + wofs)
#define STB(buf, c0) gl16(Bbase + (long)brow * 2048 + (c0) * 2 + bcol, (char*)bt[buf] + wofs)
#define BIAS(buf, j, kvl) ((float)*(const _Float16*)((const char*)bt[buf] + (w * 16 + 4 * g + (j)) * 64 + (kvl) * 2))

  // ---- pass 1: row sums of exp2(S') ----
  float ls0 = 0.f, ls1 = 0.f, ls2 = 0.f, ls3 = 0.f;
  STK(0, 0); STB(0, 0);
  {
    int buf = 0;
    for (int c0 = 0; c0 < NN; c0 += 32, buf ^= 1) {
      __syncthreads();
      if (c0 + 32 < NN) { STK(buf ^ 1, c0 + 32); STB(buf ^ 1, c0 + 32); }
      const char* kbuf = (const char*)kt[buf];
      h8 k0 = *(const h8*)(kbuf + s * 128 + ((16 * g) ^ ksw));
      h8 k1 = *(const h8*)(kbuf + s * 128 + ((64 + 16 * g) ^ ksw));
      f4 acc = __builtin_amdgcn_mfma_f32_16x16x32_f16(aQ0, k0, z4, 0, 0, 0);
      acc = __builtin_amdgcn_mfma_f32_16x16x32_f16(aQ1, k1, acc, 0, 0, 0);
      ls0 += fexp2(acc[0] + BIAS(buf, 0, s));
      ls1 += fexp2(acc[1] + BIAS(buf, 1, s));
      ls2 += fexp2(acc[2] + BIAS(buf, 2, s));
      ls3 += fexp2(acc[3] + BIAS(buf, 3, s));
      k0 = *(const h8*)(kbuf + (16 + s) * 128 + ((16 * g) ^ ksw));
      k1 = *(const h8*)(kbuf + (16 + s) * 128 + ((64 + 16 * g) ^ ksw));
      acc = __builtin_amdgcn_mfma_f32_16x16x32_f16(aQ0, k0, z4, 0, 0, 0);
      acc = __builtin_amdgcn_mfma_f32_16x16x32_f16(aQ1, k1, acc, 0, 0, 0);
      ls0 += fexp2(acc[0] + BIAS(buf, 0, 16 + s));
      ls1 += fexp2(acc[1] + BIAS(buf, 1, 16 + s));
      ls2 += fexp2(acc[2] + BIAS(buf, 2, 16 + s));
      ls3 += fexp2(acc[3] + BIAS(buf, 3, 16 + s));
    }
  }
#pragma unroll
  for (int m = 1; m < 16; m <<= 1) {
    ls0 += __shfl_xor(ls0, m, 64);
    ls1 += __shfl_xor(ls1, m, 64);
    ls2 += __shfl_xor(ls2, m, 64);
    ls3 += __shfl_xor(ls3, m, 64);
  }
  float iv0 = frcp(ls0), iv1 = frcp(ls1), iv2 = frcp(ls2), iv3 = frcp(ls3);

  // ---- pass 2: recompute S'; P via f32 LDS; full-line attn stores; PV from LDS V ----
  f4 ca0 = {0.f,0.f,0.f,0.f}, ca1 = {0.f,0.f,0.f,0.f};
  f4 ca2 = {0.f,0.f,0.f,0.f}, ca3 = {0.f,0.f,0.f,0.f};
  float* attnw = attn + ((long)bh * NN + q0) * NN;
  int sr = l >> 3, sc = (l & 7) * 4;
  __syncthreads();
  STK(0, 0); STV(0, 0); STB(0, 0);
  {
    int buf = 0;
    for (int c0 = 0; c0 < NN; c0 += 32, buf ^= 1) {
      __syncthreads();
      if (c0 + 32 < NN) { STK(buf ^ 1, c0 + 32); STV(buf ^ 1, c0 + 32); STB(buf ^ 1, c0 + 32); }
      const char* kbuf = (const char*)kt[buf];
      const char* vbuf = (const char*)vt2[buf];
      h8 k0 = *(const h8*)(kbuf + s * 128 + ((16 * g) ^ ksw));
      h8 k1 = *(const h8*)(kbuf + s * 128 + ((64 + 16 * g) ^ ksw));
      f4 acc = __builtin_amdgcn_mfma_f32_16x16x32_f16(aQ0, k0, z4, 0, 0, 0);
      acc = __builtin_amdgcn_mfma_f32_16x16x32_f16(aQ1, k1, acc, 0, 0, 0);
      pf[w][4 * g + 0][s] = fexp2(acc[0] + BIAS(buf, 0, s)) * iv0;
      pf[w][4 * g + 1][s] = fexp2(acc[1] + BIAS(buf, 1, s)) * iv1;
      pf[w][4 * g + 2][s] = fexp2(acc[2] + BIAS(buf, 2, s)) * iv2;
      pf[w][4 * g + 3][s] = fexp2(acc[3] + BIAS(buf, 3, s)) * iv3;
      k0 = *(const h8*)(kbuf + (16 + s) * 128 + ((16 * g) ^ ksw));
      k1 = *(const h8*)(kbuf + (16 + s) * 128 + ((64 + 16 * g) ^ ksw));
      acc = __builtin_amdgcn_mfma_f32_16x16x32_f16(aQ0, k0, z4, 0, 0, 0);
      acc = __builtin_amdgcn_mfma_f32_16x16x32_f16(aQ1, k1, acc, 0, 0, 0);
      pf[w][4 * g + 0][16 + s] = fexp2(acc[0] + BIAS(buf, 0, 16 + s)) * iv0;
      pf[w][4 * g + 1][16 + s] = fexp2(acc[1] + BIAS(buf, 1, 16 + s)) * iv1;
      pf[w][4 * g + 2][16 + s] = fexp2(acc[2] + BIAS(buf, 2, 16 + s)) * iv2;
      pf[w][4 * g + 3][16 + s] = fexp2(acc[3] + BIAS(buf, 3, 16 + s)) * iv3;
      f4 row0 = *reinterpret_cast<const f4*>(&pf[w][sr][sc]);
      f4 row1 = *reinterpret_cast<const f4*>(&pf[w][sr + 8][sc]);
      *reinterpret_cast<f4*>(attnw + (long)sr * NN + c0 + sc) = row0;
      *reinterpret_cast<f4*>(attnw + (long)(sr + 8) * NN + c0 + sc) = row1;
      f4 pa = *reinterpret_cast<const f4*>(&pf[w][s][8 * g]);
      f4 pb4 = *reinterpret_cast<const f4*>(&pf[w][s][8 * g + 4]);
      union { h8 v; h2 q[4]; } up;
      up.q[0] = pkrtz(pa[0], pa[1]);  up.q[1] = pkrtz(pa[2], pa[3]);
      up.q[2] = pkrtz(pb4[0], pb4[1]); up.q[3] = pkrtz(pb4[2], pb4[3]);
      h8 aP = up.v;
      h8 bv0 = *(const h8*)(vbuf + (s)      * 64 + ((16 * g) ^ vswz));
      h8 bv1 = *(const h8*)(vbuf + (16 + s) * 64 + ((16 * g) ^ vswz));
      h8 bv2 = *(const h8*)(vbuf + (32 + s) * 64 + ((16 * g) ^ vswz));
      h8 bv3 = *(const h8*)(vbuf + (48 + s) * 64 + ((16 * g) ^ vswz));
      ca0 = __builtin_amdgcn_mfma_f32_16x16x32_f16(aP, bv0, ca0, 0, 0, 0);
      ca1 = __builtin_amdgcn_mfma_f32_16x16x32_f16(aP, bv1, ca1, 0, 0, 0);
      ca2 = __builtin_amdgcn_mfma_f32_16x16x32_f16(aP, bv2, ca2, 0, 0, 0);
      ca3 = __builtin_amdgcn_mfma_f32_16x16x32_f16(aP, bv3, ca3, 0, 0, 0);
    }
  }
  float* cw = ctx + ((long)bh * NN + q0) * DK;
#pragma unroll
  for (int j = 0; j < 4; ++j) {
    cw[(4 * g + j) * DK + 0  + s] = ca0[j];
    cw[(4 * g + j) * DK + 16 + s] = ca1[j];
    cw[(4 * g + j) * DK + 32 + s] = ca2[j];
    cw[(4 * g + j) * DK + 48 + s] = ca3[j];
  }
#undef STK
#undef STV
#undef STB
#undef BIAS
}

extern "C" void kernel_launch(void* const* d_in, const int* in_sizes, int n_in,
                              void* d_out, int out_size, void* d_ws, size_t ws_size,
                              hipStream_t stream) {
  const float* Q = (const float*)d_in[0];
  const float* K = (const float*)d_in[1];
  const float* V = (const float*)d_in[2];
  const void* mask = d_in[3];
  const float* edge = (const float*)d_in[4];
  const float* W1 = (const float*)d_in[5];
  const float* b1 = (const float*)d_in[6];
  const float* W2 = (const float*)d_in[7];
  const float* b2 = (const float*)d_in[8];
  float* ctx = (float*)d_out;
  float* attn = ctx + QSZ;                  // outputs: context then attn
  char* ws = (char*)d_ws;
  if (ws_size < WS_NEED) return;
  _Float16* Qh = (_Float16*)(ws + OFF_QH);
  _Float16* Kh = (_Float16*)(ws + OFF_KH);
  _Float16* Vt = (_Float16*)(ws + OFF_VT);
  _Float16* biasM = (_Float16*)(ws + OFF_BIAS);
  int* flag = (int*)(ws + OFF_FLAG);

  k_detect<<<1, 256, 0, stream>>>((const unsigned char*)mask, flag);
  k_prep<<<9216, 256, 0, stream>>>(Q, K, V, Qh, Kh, Vt);
  k_bias<<<8192, 256, 0, stream>>>(edge, mask, W1, b1, W2, b2, flag, biasM);
  k_attn<<<1024, 256, 0, stream>>>(Qh, Kh, Vt, biasM, ctx, attn);
}

// Round 13
// 266.837 us; speedup vs baseline: 1.6307x; 1.1355x over previous
//
#include <hip/hip_runtime.h>
#include <stdint.h>

// Problem constants
constexpr int NB = 8, NH = 8, NN = 1024, DK = 64, ED = 16;
constexpr long QSZ = (long)NB * NH * NN * DK;       // 4,194,304

typedef _Float16 h8 __attribute__((ext_vector_type(8)));
typedef _Float16 h4 __attribute__((ext_vector_type(4)));
typedef _Float16 h2 __attribute__((ext_vector_type(2)));
typedef float f4 __attribute__((ext_vector_type(4)));
typedef float fv16 __attribute__((ext_vector_type(16)));

// ws layout (bytes)
constexpr size_t OFF_QH = 0;                         // 8 MiB fp16 (pre-scaled by 0.125*log2e)
constexpr size_t OFF_KH = 8388608;                   // 8 MiB fp16
constexpr size_t OFF_VT = 16777216;                  // 8 MiB fp16 (transposed [bh][d][k])
constexpr size_t OFF_BIAS = 25165824;                // 16 MiB fp16 (bias*log2e, masked=-30000)
constexpr size_t WS_NEED = OFF_BIAS + 16777216;

constexpr float LG2E = 1.4426950408889634f;          // log2(e)
constexpr float C2 = 2.8853900817779268f;            // 2*log2(e)
constexpr float QS = 0.125f * LG2E;                  // fold 1/sqrt(dk) and log2e into Q

static __device__ __forceinline__ float fexp2(float x) {
  float r; asm("v_exp_f32 %0, %1" : "=v"(r) : "v"(x)); return r;
}
static __device__ __forceinline__ float frcp(float x) {
  float r; asm("v_rcp_f32 %0, %1" : "=v"(r) : "v"(x)); return r;
}
static __device__ __forceinline__ h2 pkrtz(float a, float b) {
  return __builtin_bit_cast(h2, __builtin_amdgcn_cvt_pkrtz(a, b));
}
// async global->LDS, 16B per lane; lptr must be WAVE-UNIFORM (HW scatters lane i to lptr + i*16)
static __device__ __forceinline__ void gl16(const void* g, void* l) {
  __builtin_amdgcn_global_load_lds(
      (const __attribute__((address_space(1))) uint32_t*)g,
      (__attribute__((address_space(3))) uint32_t*)l, 16, 0, 0);
}

// ---------- merged front kernel: bias MLP (blocks 0..8191) + Q/K/V prep (8192..17407) ----------
// Bias blocks self-detect mask width (scan first 4KB: int32 0/1 never has nonzero
// bytes at %4!=0) -> no separate detect dispatch, no flag dependency.
__global__ __launch_bounds__(256, 3) void k_front(
    const float* __restrict__ Q, const float* __restrict__ K, const float* __restrict__ V,
    const void* __restrict__ maskp, const float* __restrict__ edge,
    const float* __restrict__ W1, const float* __restrict__ b1,
    const float* __restrict__ W2, const float* __restrict__ b2,
    _Float16* __restrict__ Qh, _Float16* __restrict__ Kh, _Float16* __restrict__ Vt,
    _Float16* __restrict__ biasM) {
  int bid = blockIdx.x;
  int tid = threadIdx.x;
  if (bid >= 8192) {
    // ---------------- prep path ----------------
    int pb_ = bid - 8192;
    if (pb_ < 8192) {
      int i = pb_ * 256 + tid;
      const int n4 = (int)(QSZ / 4);
      if (i < n4) {
        float4 v = reinterpret_cast<const float4*>(Q)[i];
        h4 o; o[0] = (_Float16)(v.x * QS); o[1] = (_Float16)(v.y * QS);
              o[2] = (_Float16)(v.z * QS); o[3] = (_Float16)(v.w * QS);
        reinterpret_cast<h4*>(Qh)[i] = o;
      } else {
        int j = i - n4;
        float4 v = reinterpret_cast<const float4*>(K)[j];
        h4 o; o[0] = (_Float16)v.x; o[1] = (_Float16)v.y;
              o[2] = (_Float16)v.z; o[3] = (_Float16)v.w;
        reinterpret_cast<h4*>(Kh)[j] = o;
      }
    } else {
      int wid = ((pb_ - 8192) * 256 + tid) >> 6;
      int lane = tid & 63;
      int bh = wid >> 6;
      int k0 = (wid & 63) << 4;
      const float* Vb = V + (long)bh * NN * DK;
      _Float16* Vo = Vt + (long)bh * DK * NN + (long)lane * NN + k0;
      h8 p0, p1;
#pragma unroll
      for (int i = 0; i < 16; ++i) {
        float v = Vb[(long)(k0 + i) * DK + lane];
        if (i < 8) p0[i] = (_Float16)v; else p1[i - 8] = (_Float16)v;
      }
      *reinterpret_cast<h8*>(Vo) = p0;
      *reinterpret_cast<h8*>(Vo + 8) = p1;
    }
    return;
  }
  // ---------------- bias path ----------------
  int bq = bid;
  int w = tid >> 6, l = tid & 63;
  int h = l >> 5, c31 = l & 31;

  // self-detect mask element width: scan first 4096 bytes (coalesced, L2-hot)
  __shared__ int sh4[4];
  {
    int4 mv = reinterpret_cast<const int4*>(maskp)[tid];
    int any = (mv.x | mv.y | mv.z | mv.w) & 0xFFFFFF00;
    unsigned long long bal = __ballot(any != 0);
    if ((tid & 63) == 0) sh4[tid >> 6] = (bal != 0) ? 1 : 0;
  }
  __syncthreads();
  bool isbool = (sh4[0] | sh4[1] | sh4[2] | sh4[3]) != 0;

  h8 aw0, aw1;
#pragma unroll
  for (int j = 0; j < 8; ++j) {
    aw0[j] = (_Float16)(W1[(8 * h + j) * 64 + 0  + c31] * C2);
    aw1[j] = (_Float16)(W1[(8 * h + j) * 64 + 32 + c31] * C2);
  }
  h2 pb[16], pw[16];
  float sw = 0.f;
#pragma unroll
  for (int r = 0; r < 16; ++r) {
    int dr = (r & 3) + 8 * (r >> 2) + 4 * h;
    float b0 = b1[dr] * C2, b1v = b1[32 + dr] * C2;
    float w0 = W2[dr], w1v = W2[32 + dr];
    pb[r] = pkrtz(b0, b1v);
    pw[r] = pkrtz(w0, w1v);
    sw += w0 + w1v;
  }
  sw += __shfl_xor(sw, 32, 64);
  float base = (sw + b2[0]) * LG2E;

  const char* erow_b = (const char*)(edge + (long)bq * NN * ED);  // 64B per kv row
  _Float16* orow = biasM + (long)bq * NN;
  const int* mrowi = (const int*)maskp + (long)bq * NN;
  const unsigned char* mrowb = (const unsigned char*)maskp + (long)bq * NN;

  fv16 z;
#pragma unroll
  for (int r = 0; r < 16; ++r) z[r] = 0.f;

  int kq0 = w * 256;
  int m4[4];
#pragma unroll
  for (int p = 0; p < 4; ++p) {
    int idx = kq0 + p * 64 + 32 * h + c31;
    m4[p] = isbool ? (int)mrowb[idx] : mrowi[idx];
  }

  __shared__ __align__(16) float ebuf[4][2][1024];
  int r4 = l >> 2;
  int csw = ((l & 3) * 16) ^ ((r4 & 3) << 4);
#define STAGE(buf, p) do { \
    const char* src_ = erow_b + (long)(kq0 + (p) * 64) * 64; \
    char* dst_ = (char*)&ebuf[w][buf][0]; \
    gl16(src_ + (long)(r4) * 64 + csw, dst_); \
    gl16(src_ + (long)(16 + r4) * 64 + csw, dst_ + 1024); \
    gl16(src_ + (long)(32 + r4) * 64 + csw, dst_ + 2048); \
    gl16(src_ + (long)(48 + r4) * 64 + csw, dst_ + 3072); \
  } while (0)

  int sw0 = (c31 & 3) << 4;
  float res[4];
  STAGE(0, 0);
#pragma unroll
  for (int p = 0; p < 4; ++p) {
    if (p < 3) STAGE((p + 1) & 1, p + 1);
    if (p < 3) { asm volatile("s_waitcnt vmcnt(4)" ::: "memory"); }
    else       { asm volatile("s_waitcnt vmcnt(0)" ::: "memory"); }
    const char* tb = (const char*)&ebuf[w][p & 1][0];
    f4 e0a = *(const f4*)(tb + c31 * 64 + ((h * 32) ^ sw0));
    f4 e0b = *(const f4*)(tb + c31 * 64 + ((h * 32 + 16) ^ sw0));
    f4 e1a = *(const f4*)(tb + (32 + c31) * 64 + ((h * 32) ^ sw0));
    f4 e1b = *(const f4*)(tb + (32 + c31) * 64 + ((h * 32 + 16) ^ sw0));
    union { h8 v; h2 q[4]; } u0, u1;
    u0.q[0] = pkrtz(e0a[0], e0a[1]); u0.q[1] = pkrtz(e0a[2], e0a[3]);
    u0.q[2] = pkrtz(e0b[0], e0b[1]); u0.q[3] = pkrtz(e0b[2], e0b[3]);
    u1.q[0] = pkrtz(e1a[0], e1a[1]); u1.q[1] = pkrtz(e1a[2], e1a[3]);
    u1.q[2] = pkrtz(e1b[0], e1b[1]); u1.q[3] = pkrtz(e1b[2], e1b[3]);
    float a00 = 0.f, a01 = 0.f, a10 = 0.f, a11 = 0.f;
    {
      fv16 hA0 = __builtin_amdgcn_mfma_f32_32x32x16_f16(aw0, u0.v, z, 0, 0, 0);
      fv16 hA1 = __builtin_amdgcn_mfma_f32_32x32x16_f16(aw0, u1.v, z, 0, 0, 0);
#pragma unroll
      for (int r = 0; r < 16; ++r) {
        float bb = (float)pb[r][0];
        float ww = (float)pw[r][0];
        if (r & 1) {
          a01 = fmaf(ww, frcp(fexp2(hA0[r] + bb) + 1.f), a01);
          a11 = fmaf(ww, frcp(fexp2(hA1[r] + bb) + 1.f), a11);
        } else {
          a00 = fmaf(ww, frcp(fexp2(hA0[r] + bb) + 1.f), a00);
          a10 = fmaf(ww, frcp(fexp2(hA1[r] + bb) + 1.f), a10);
        }
      }
    }
    {
      fv16 hB0 = __builtin_amdgcn_mfma_f32_32x32x16_f16(aw1, u0.v, z, 0, 0, 0);
      fv16 hB1 = __builtin_amdgcn_mfma_f32_32x32x16_f16(aw1, u1.v, z, 0, 0, 0);
#pragma unroll
      for (int r = 0; r < 16; ++r) {
        float bb = (float)pb[r][1];
        float ww = (float)pw[r][1];
        if (r & 1) {
          a01 = fmaf(ww, frcp(fexp2(hB0[r] + bb) + 1.f), a01);
          a11 = fmaf(ww, frcp(fexp2(hB1[r] + bb) + 1.f), a11);
        } else {
          a00 = fmaf(ww, frcp(fexp2(hB0[r] + bb) + 1.f), a00);
          a10 = fmaf(ww, frcp(fexp2(hB1[r] + bb) + 1.f), a10);
        }
      }
    }
    float p0 = a00 + a01;
    float p1 = a10 + a11;
    p0 += __shfl_xor(p0, 32, 64);
    p1 += __shfl_xor(p1, 32, 64);
    res[p] = h ? p1 : p0;
  }
#undef STAGE
#pragma unroll
  for (int p = 0; p < 4; ++p) {
    int idx = kq0 + p * 64 + 32 * h + c31;
    orow[idx] = m4[p] ? (_Float16)(-30000.0f) : (_Float16)fmaf(-C2, res[p], base);
  }
}

// ---------- fused attention (unchanged from R11/R12 winner) ----------
__global__ __launch_bounds__(256) void k_attn(
    const _Float16* __restrict__ Qh, const _Float16* __restrict__ Kh,
    const _Float16* __restrict__ Vt, const _Float16* __restrict__ biasH,
    float* __restrict__ ctx, float* __restrict__ attn) {
  int bid = blockIdx.x;
  int b = bid & 7;           // XCD-pinned batch
  int t_ = bid >> 3;
  int hh = t_ & 7;
  int qb = t_ >> 3;
  int bh = b * 8 + hh;
  int tid = threadIdx.x;
  int w = tid >> 6, l = tid & 63;
  int g = l >> 4, s = l & 15;
  int q0 = qb * 64 + w * 16;

  const _Float16* Qw = Qh + ((long)bh * NN + q0) * DK;
  const char* Kbase = (const char*)(Kh + (long)bh * NN * DK);
  const char* Vbase = (const char*)(Vt + (long)bh * DK * NN);
  const char* Bbase = (const char*)(biasH + (long)b * NN * NN + (long)(qb * 64) * NN);
  h8 aQ0 = *reinterpret_cast<const h8*>(Qw + s * DK + 8 * g);
  h8 aQ1 = *reinterpret_cast<const h8*>(Qw + s * DK + 32 + 8 * g);
  const f4 z4 = {0.f, 0.f, 0.f, 0.f};

  __shared__ __align__(16) _Float16 kt[2][32 * 64];
  __shared__ __align__(16) _Float16 vt2[2][64 * 32];
  __shared__ __align__(16) _Float16 bt[2][64 * 32];
  __shared__ float pf[4][16][33];

  int krow = tid >> 3;
  int kcol = ((tid & 7) * 16) ^ ((krow & 7) << 4);
  int vrow = tid >> 2;
  int vcol = ((tid & 3) * 16) ^ ((vrow & 3) << 4);
  int brow = tid >> 2;
  int bcol = (tid & 3) * 16;
  int wofs = w << 10;

  int ksw = (s & 7) << 4;
  int vswz = (s & 3) << 4;

#define STK(buf, c0) gl16(Kbase + (long)((c0) + krow) * 128 + kcol, (char*)kt[buf] + wofs)
#define STV(buf, c0) gl16(Vbase + (long)vrow * 2048 + (c0) * 2 + vcol, (char*)vt2[buf] + wofs)
#define STB(buf, c0) gl16(Bbase + (long)brow * 2048 + (c0) * 2 + bcol, (char*)bt[buf] + wofs)
#define BIAS(buf, j, kvl) ((float)*(const _Float16*)((const char*)bt[buf] + (w * 16 + 4 * g + (j)) * 64 + (kvl) * 2))

  float ls0 = 0.f, ls1 = 0.f, ls2 = 0.f, ls3 = 0.f;
  STK(0, 0); STB(0, 0);
  {
    int buf = 0;
    for (int c0 = 0; c0 < NN; c0 += 32, buf ^= 1) {
      __syncthreads();
      if (c0 + 32 < NN) { STK(buf ^ 1, c0 + 32); STB(buf ^ 1, c0 + 32); }
      const char* kbuf = (const char*)kt[buf];
      h8 k0 = *(const h8*)(kbuf + s * 128 + ((16 * g) ^ ksw));
      h8 k1 = *(const h8*)(kbuf + s * 128 + ((64 + 16 * g) ^ ksw));
      f4 acc = __builtin_amdgcn_mfma_f32_16x16x32_f16(aQ0, k0, z4, 0, 0, 0);
      acc = __builtin_amdgcn_mfma_f32_16x16x32_f16(aQ1, k1, acc, 0, 0, 0);
      ls0 += fexp2(acc[0] + BIAS(buf, 0, s));
      ls1 += fexp2(acc[1] + BIAS(buf, 1, s));
      ls2 += fexp2(acc[2] + BIAS(buf, 2, s));
      ls3 += fexp2(acc[3] + BIAS(buf, 3, s));
      k0 = *(const h8*)(kbuf + (16 + s) * 128 + ((16 * g) ^ ksw));
      k1 = *(const h8*)(kbuf + (16 + s) * 128 + ((64 + 16 * g) ^ ksw));
      acc = __builtin_amdgcn_mfma_f32_16x16x32_f16(aQ0, k0, z4, 0, 0, 0);
      acc = __builtin_amdgcn_mfma_f32_16x16x32_f16(aQ1, k1, acc, 0, 0, 0);
      ls0 += fexp2(acc[0] + BIAS(buf, 0, 16 + s));
      ls1 += fexp2(acc[1] + BIAS(buf, 1, 16 + s));
      ls2 += fexp2(acc[2] + BIAS(buf, 2, 16 + s));
      ls3 += fexp2(acc[3] + BIAS(buf, 3, 16 + s));
    }
  }
#pragma unroll
  for (int m = 1; m < 16; m <<= 1) {
    ls0 += __shfl_xor(ls0, m, 64);
    ls1 += __shfl_xor(ls1, m, 64);
    ls2 += __shfl_xor(ls2, m, 64);
    ls3 += __shfl_xor(ls3, m, 64);
  }
  float iv0 = frcp(ls0), iv1 = frcp(ls1), iv2 = frcp(ls2), iv3 = frcp(ls3);

  f4 ca0 = {0.f,0.f,0.f,0.f}, ca1 = {0.f,0.f,0.f,0.f};
  f4 ca2 = {0.f,0.f,0.f,0.f}, ca3 = {0.f,0.f,0.f,0.f};
  float* attnw = attn + ((long)bh * NN + q0) * NN;
  int sr = l >> 3, sc = (l & 7) * 4;
  __syncthreads();
  STK(0, 0); STV(0, 0); STB(0, 0);
  {
    int buf = 0;
    for (int c0 = 0; c0 < NN; c0 += 32, buf ^= 1) {
      __syncthreads();
      if (c0 + 32 < NN) { STK(buf ^ 1, c0 + 32); STV(buf ^ 1, c0 + 32); STB(buf ^ 1, c0 + 32); }
      const char* kbuf = (const char*)kt[buf];
      const char* vbuf = (const char*)vt2[buf];
      h8 k0 = *(const h8*)(kbuf + s * 128 + ((16 * g) ^ ksw));
      h8 k1 = *(const h8*)(kbuf + s * 128 + ((64 + 16 * g) ^ ksw));
      f4 acc = __builtin_amdgcn_mfma_f32_16x16x32_f16(aQ0, k0, z4, 0, 0, 0);
      acc = __builtin_amdgcn_mfma_f32_16x16x32_f16(aQ1, k1, acc, 0, 0, 0);
      pf[w][4 * g + 0][s] = fexp2(acc[0] + BIAS(buf, 0, s)) * iv0;
      pf[w][4 * g + 1][s] = fexp2(acc[1] + BIAS(buf, 1, s)) * iv1;
      pf[w][4 * g + 2][s] = fexp2(acc[2] + BIAS(buf, 2, s)) * iv2;
      pf[w][4 * g + 3][s] = fexp2(acc[3] + BIAS(buf, 3, s)) * iv3;
      k0 = *(const h8*)(kbuf + (16 + s) * 128 + ((16 * g) ^ ksw));
      k1 = *(const h8*)(kbuf + (16 + s) * 128 + ((64 + 16 * g) ^ ksw));
      acc = __builtin_amdgcn_mfma_f32_16x16x32_f16(aQ0, k0, z4, 0, 0, 0);
      acc = __builtin_amdgcn_mfma_f32_16x16x32_f16(aQ1, k1, acc, 0, 0, 0);
      pf[w][4 * g + 0][16 + s] = fexp2(acc[0] + BIAS(buf, 0, 16 + s)) * iv0;
      pf[w][4 * g + 1][16 + s] = fexp2(acc[1] + BIAS(buf, 1, 16 + s)) * iv1;
      pf[w][4 * g + 2][16 + s] = fexp2(acc[2] + BIAS(buf, 2, 16 + s)) * iv2;
      pf[w][4 * g + 3][16 + s] = fexp2(acc[3] + BIAS(buf, 3, 16 + s)) * iv3;
      f4 row0 = *reinterpret_cast<const f4*>(&pf[w][sr][sc]);
      f4 row1 = *reinterpret_cast<const f4*>(&pf[w][sr + 8][sc]);
      *reinterpret_cast<f4*>(attnw + (long)sr * NN + c0 + sc) = row0;
      *reinterpret_cast<f4*>(attnw + (long)(sr + 8) * NN + c0 + sc) = row1;
      f4 pa = *reinterpret_cast<const f4*>(&pf[w][s][8 * g]);
      f4 pb4 = *reinterpret_cast<const f4*>(&pf[w][s][8 * g + 4]);
      union { h8 v; h2 q[4]; } up;
      up.q[0] = pkrtz(pa[0], pa[1]);  up.q[1] = pkrtz(pa[2], pa[3]);
      up.q[2] = pkrtz(pb4[0], pb4[1]); up.q[3] = pkrtz(pb4[2], pb4[3]);
      h8 aP = up.v;
      h8 bv0 = *(const h8*)(vbuf + (s)      * 64 + ((16 * g) ^ vswz));
      h8 bv1 = *(const h8*)(vbuf + (16 + s) * 64 + ((16 * g) ^ vswz));
      h8 bv2 = *(const h8*)(vbuf + (32 + s) * 64 + ((16 * g) ^ vswz));
      h8 bv3 = *(const h8*)(vbuf + (48 + s) * 64 + ((16 * g) ^ vswz));
      ca0 = __builtin_amdgcn_mfma_f32_16x16x32_f16(aP, bv0, ca0, 0, 0, 0);
      ca1 = __builtin_amdgcn_mfma_f32_16x16x32_f16(aP, bv1, ca1, 0, 0, 0);
      ca2 = __builtin_amdgcn_mfma_f32_16x16x32_f16(aP, bv2, ca2, 0, 0, 0);
      ca3 = __builtin_amdgcn_mfma_f32_16x16x32_f16(aP, bv3, ca3, 0, 0, 0);
    }
  }
  float* cw = ctx + ((long)bh * NN + q0) * DK;
#pragma unroll
  for (int j = 0; j < 4; ++j) {
    cw[(4 * g + j) * DK + 0  + s] = ca0[j];
    cw[(4 * g + j) * DK + 16 + s] = ca1[j];
    cw[(4 * g + j) * DK + 32 + s] = ca2[j];
    cw[(4 * g + j) * DK + 48 + s] = ca3[j];
  }
#undef STK
#undef STV
#undef STB
#undef BIAS
}

extern "C" void kernel_launch(void* const* d_in, const int* in_sizes, int n_in,
                              void* d_out, int out_size, void* d_ws, size_t ws_size,
                              hipStream_t stream) {
  const float* Q = (const float*)d_in[0];
  const float* K = (const float*)d_in[1];
  const float* V = (const float*)d_in[2];
  const void* mask = d_in[3];
  const float* edge = (const float*)d_in[4];
  const float* W1 = (const float*)d_in[5];
  const float* b1 = (const float*)d_in[6];
  const float* W2 = (const float*)d_in[7];
  const float* b2 = (const float*)d_in[8];
  float* ctx = (float*)d_out;
  float* attn = ctx + QSZ;                  // outputs: context then attn
  char* ws = (char*)d_ws;
  if (ws_size < WS_NEED) return;
  _Float16* Qh = (_Float16*)(ws + OFF_QH);
  _Float16* Kh = (_Float16*)(ws + OFF_KH);
  _Float16* Vt = (_Float16*)(ws + OFF_VT);
  _Float16* biasM = (_Float16*)(ws + OFF_BIAS);

  k_front<<<17408, 256, 0, stream>>>(Q, K, V, mask, edge, W1, b1, W2, b2,
                                     Qh, Kh, Vt, biasM);
  k_attn<<<1024, 256, 0, stream>>>(Qh, Kh, Vt, biasM, ctx, attn);
}